// Round 13
// baseline (3176.787 us; speedup 1.0000x reference)
//
#include <hip/hip_runtime.h>

#define T_DIM 8192
#define N_DIM 8
#define C_DIM 64
#define KB    2048
#define NT    (N_DIM * T_DIM)        // 65536 rows
#define TOTX  ((size_t)NT * C_DIM)   // 4194304 elements
#define NBLK  2048                   // argmin blocks (32 rows each)
#define LISTCAP 8192
#define TAU   1e-3f

// Scratch inside out's x_d region (out + NT), overwritten LAST by xd_kernel.
// Offsets in FLOAT units from out+NT:
#define SCR_COUNT 0                   // int
#define SCR_LIST  16                  // int[8192]       -> ends 8208
#define SCR_PART  8448                // float[2048][8]  -> ends 24832
#define SCR_KNS   24832               // float[2048]     -> ends 26880
#define SCR_KK    26880               // float[2048]     -> ends 28928
#define SCR_K     32768               // f16x8[16][2048] (512 KB) -> ends 163840

typedef _Float16 half_t;
typedef _Float16 f16x8 __attribute__((ext_vector_type(8)));
typedef float    f32x16 __attribute__((ext_vector_type(16)));

// numpy pairwise sum (n=64) of squares (np-exact, fixup path).
__device__ __forceinline__ float np_sumsq64(const float* __restrict__ a) {
    float r[8];
    #pragma unroll
    for (int j = 0; j < 8; ++j) r[j] = __fmul_rn(a[j], a[j]);
    #pragma unroll
    for (int i = 8; i < 64; i += 8)
        #pragma unroll
        for (int j = 0; j < 8; ++j)
            r[j] = __fadd_rn(r[j], __fmul_rn(a[i + j], a[i + j]));
    return __fadd_rn(__fadd_rn(__fadd_rn(r[0], r[1]), __fadd_rn(r[2], r[3])),
                     __fadd_rn(__fadd_rn(r[4], r[5]), __fadd_rn(r[6], r[7])));
}

// ------------------------------------------------------------------ k prep ----
// kscr[ch][0:1024)=hi slots [slot][bin], [1024:2048)=lo. hi=-2*k_hi,
// lo=-4096*(k-k_hi). kns=seq-fma ||k||^2 (filter); kk=np-exact (fixup).
__global__ __launch_bounds__(256) void kprep_kernel(const float* __restrict__ k,
                                                    float* __restrict__ out) {
    float* base = out + NT;
    const int bin = blockIdx.x * 256 + threadIdx.x;   // grid 8 -> 2048
    if (bin == 0) ((int*)base)[SCR_COUNT] = 0;

    float kv[64];
    #pragma unroll
    for (int i = 0; i < 16; ++i)
        *(float4*)&kv[i * 4] = *(const float4*)(k + (size_t)bin * 64 + i * 4);

    float kn = 0.f;
    #pragma unroll
    for (int c = 0; c < 64; ++c) kn = fmaf(kv[c], kv[c], kn);
    base[SCR_KNS + bin] = kn;
    base[SCR_KK + bin]  = np_sumsq64(kv);

    f16x8* kscr = (f16x8*)(base + SCR_K);
    const int ch = bin >> 7, b127 = bin & 127;
    #pragma unroll
    for (int slot = 0; slot < 8; ++slot) {
        f16x8 h8, l8;
        #pragma unroll
        for (int e = 0; e < 8; ++e) {
            float xv = kv[slot * 8 + e];
            half_t hh = (half_t)xv;
            h8[e] = (half_t)(-2.f * (float)hh);
            l8[e] = (half_t)(-4096.f * (xv - (float)hh));
        }
        kscr[(size_t)ch * 2048 + slot * 128 + b127]        = h8;
        kscr[(size_t)ch * 2048 + 1024 + slot * 128 + b127] = l8;
    }
}

// ------------------------------------------------------------------ argmin ----
// Block: 32 rows, 4 waves; wave w owns bins [w*512,(w+1)*512). Reg-direct
// B-loads (no k-loop barriers), 4/SIMD occupancy, in-block quarter merge.
__global__ __launch_bounds__(256, 4) void argmin_kernel(const float* __restrict__ x,
                                                        const float* __restrict__ mask,
                                                        float* __restrict__ out) {
    __shared__ __align__(16) f16x8 xhi_s[256];   // [8 slots][32 rows]
    __shared__ __align__(16) f16x8 xlo_s[256];
    __shared__ float kns_s[2048];
    __shared__ float psx[8][32], psxx[8][32];
    __shared__ float wres[4][32][3];

    float* base = out + NT;
    const int tid = threadIdx.x;
    const int l   = tid & 63, w = tid >> 6;
    const int col = l & 31, kg = l >> 5;
    const int r0  = blockIdx.x * 32;
    const int n   = r0 >> 13;
    const int t0  = r0 & (T_DIM - 1);

    #pragma unroll
    for (int i = 0; i < 8; ++i)
        kns_s[i * 256 + tid] = base[SCR_KNS + i * 256 + tid];

    // prologue: thread (slot=tid>>5, row=tid&31) loads 8 dims, splits hi/lo
    {
        const int slot = tid >> 5, row = tid & 31;
        float sx = 0.f, sxx = 0.f;
        f16x8 h8, l8;
        #pragma unroll
        for (int e = 0; e < 8; ++e) {
            float v = x[((size_t)n * C_DIM + slot * 8 + e) * T_DIM + t0 + row];
            half_t hh = (half_t)v;
            h8[e] = hh;
            l8[e] = (half_t)(2048.f * (v - (float)hh));
            sx += v; sxx = fmaf(v, v, sxx);
        }
        xhi_s[slot * 32 + row] = h8;
        xlo_s[slot * 32 + row] = l8;
        psx[slot][row]  = sx;
        psxx[slot][row] = sxx;
    }
    __syncthreads();

    // A fragments (32 rows, K=64 over 4 k-steps)
    f16x8 a_hi[4], a_lo[4];
    #pragma unroll
    for (int s = 0; s < 4; ++s) {
        a_hi[s] = xhi_s[(2 * s + kg) * 32 + col];
        a_lo[s] = xlo_s[(2 * s + kg) * 32 + col];
    }

    // per-wave k base: quarter w -> tiles T = w*16 + t
    const f16x8* kfw = (const f16x8*)(base + SCR_K) + (size_t)w * 4 * 2048 + kg * 128 + col;
    const int binw = w * 512 + col;

    float bestv[16], best2v[16];
    int   bestb[16];
    #pragma unroll
    for (int r = 0; r < 16; ++r) {
        bestv[r] = __builtin_inff(); best2v[r] = __builtin_inff(); bestb[r] = 0;
    }

    f16x8 bhA[4], blA[4], bhB[4], blB[4];
    f16x8 bhC[4], blC[4], bhD[4], blD[4];

#define LOADT(t, BH, BL)                                                    \
    {                                                                       \
        const f16x8* p = kfw + (((t) >> 2) * 2048 + ((t) & 3) * 32);        \
        BH[0] = p[0];    BH[1] = p[256];  BH[2] = p[512];  BH[3] = p[768];  \
        BL[0] = p[1024]; BL[1] = p[1280]; BL[2] = p[1536]; BL[3] = p[1792]; \
    }

#define COMPT(t, BH, BL)                                                     \
    {                                                                        \
        const float kn = kns_s[binw + (t) * 32];                             \
        f32x16 acc1, acc2;                                                   \
        _Pragma("unroll")                                                    \
        for (int r = 0; r < 16; ++r) { acc1[r] = kn; acc2[r] = 0.f; }        \
        _Pragma("unroll")                                                    \
        for (int s = 0; s < 4; ++s) {                                        \
            acc1 = __builtin_amdgcn_mfma_f32_32x32x16_f16(a_hi[s], BH[s], acc1, 0, 0, 0); \
            acc2 = __builtin_amdgcn_mfma_f32_32x32x16_f16(a_hi[s], BL[s], acc2, 0, 0, 0); \
            acc2 = __builtin_amdgcn_mfma_f32_32x32x16_f16(a_lo[s], BH[s], acc2, 0, 0, 0); \
        }                                                                    \
        const int binf = binw + (t) * 32;                                    \
        _Pragma("unroll")                                                    \
        for (int r = 0; r < 16; ++r) {                                       \
            float sv = fmaf(acc2[r], 4.8828125e-4f, acc1[r]);                \
            best2v[r] = fminf(best2v[r], fmaxf(sv, bestv[r]));               \
            if (sv < bestv[r]) { bestv[r] = sv; bestb[r] = binf; }           \
        }                                                                    \
    }

    LOADT(0, bhA, blA);  LOADT(1, bhB, blB);
    LOADT(2, bhC, blC);  COMPT(0, bhA, blA);
    LOADT(3, bhD, blD);  COMPT(1, bhB, blB);
    LOADT(4, bhA, blA);  COMPT(2, bhC, blC);
    LOADT(5, bhB, blB);  COMPT(3, bhD, blD);
    LOADT(6, bhC, blC);  COMPT(4, bhA, blA);
    LOADT(7, bhD, blD);  COMPT(5, bhB, blB);
    LOADT(8, bhA, blA);  COMPT(6, bhC, blC);
    LOADT(9, bhB, blB);  COMPT(7, bhD, blD);
    LOADT(10, bhC, blC); COMPT(8, bhA, blA);
    LOADT(11, bhD, blD); COMPT(9, bhB, blB);
    LOADT(12, bhA, blA); COMPT(10, bhC, blC);
    LOADT(13, bhB, blB); COMPT(11, bhD, blD);
    LOADT(14, bhC, blC); COMPT(12, bhA, blA);
    LOADT(15, bhD, blD); COMPT(13, bhB, blB);
    COMPT(14, bhC, blC); COMPT(15, bhD, blD);
#undef LOADT
#undef COMPT

    // merge across the 32 column-lanes of each half, tracking 2nd-best
    #pragma unroll
    for (int off = 1; off <= 16; off <<= 1) {
        #pragma unroll
        for (int r = 0; r < 16; ++r) {
            float ov = __shfl_xor(bestv[r], off, 64);
            int   ob = __shfl_xor(bestb[r], off, 64);
            float o2 = __shfl_xor(best2v[r], off, 64);
            float mx = fmaxf(bestv[r], ov);
            best2v[r] = fminf(fminf(best2v[r], o2), mx);
            if (ov < bestv[r] || (ov == bestv[r] && ob < bestb[r])) {
                bestv[r] = ov; bestb[r] = ob;
            }
        }
    }

    // stash per-(quarter,row) results
    if (col == 0) {
        #pragma unroll
        for (int r = 0; r < 16; ++r) {
            const int row_loc = 4 * kg + (r & 3) + 8 * (r >> 2);
            wres[w][row_loc][0] = bestv[r];
            wres[w][row_loc][1] = best2v[r];
            wres[w][row_loc][2] = __int_as_float(bestb[r]);
        }
    }
    __syncthreads();

    // final merge: thread < 32 owns one row
    if (tid < 32) {
        const int row = tid;
        float v0 = wres[0][row][0], v1 = wres[1][row][0];
        float v2 = wres[2][row][0], v3 = wres[3][row][0];
        float bv = v0; int bb = __float_as_int(wres[0][row][2]);
        if (v1 < bv) { bv = v1; bb = __float_as_int(wres[1][row][2]); }
        if (v2 < bv) { bv = v2; bb = __float_as_int(wres[2][row][2]); }
        if (v3 < bv) { bv = v3; bb = __float_as_int(wres[3][row][2]); }
        float m01 = fminf(v0, v1), M01 = fmaxf(v0, v1);
        float m23 = fminf(v2, v3), M23 = fmaxf(v2, v3);
        float sec = fminf(fmaxf(m01, m23), fminf(M01, M23));
        float b2  = fminf(sec, fminf(fminf(wres[0][row][1], wres[1][row][1]),
                                     fminf(wres[2][row][1], wres[3][row][1])));

        out[r0 + row] = (float)bb;
        if (b2 - bv < TAU) {
            int idx = atomicAdd((int*)base + SCR_COUNT, 1);
            if (idx < LISTCAP) ((int*)base + SCR_LIST)[idx] = r0 + row;
        }
        float sx = 0.f, sxx = 0.f;
        #pragma unroll
        for (int s = 0; s < 8; ++s) { sx += psx[s][row]; sxx += psxx[s][row]; }
        const float m  = mask[r0 + row];
        const float d2 = sxx + bv;
        float vals[5] = { m * d2, d2, m, sx, sxx };
        #pragma unroll
        for (int off = 1; off <= 16; off <<= 1)
            #pragma unroll
            for (int q = 0; q < 5; ++q) vals[q] += __shfl_xor(vals[q], off, 64);
        if (tid == 0) {
            float* partials = base + SCR_PART;
            #pragma unroll
            for (int q = 0; q < 5; ++q)
                partials[(size_t)blockIdx.x * 8 + q] = vals[q];
        }
    }
}

// ------------------------------------------------------------------ fixup ----
// np-f32-exact recompute of flagged near-tie rows (first-occurrence argmin).
__global__ __launch_bounds__(256) void fixup_kernel(const float* __restrict__ x,
                                                    const float* __restrict__ k,
                                                    float* __restrict__ out) {
    __shared__ float xv[C_DIM];
    __shared__ float sxxs;
    __shared__ float redv[4];
    __shared__ int   redb[4];
    const int tid = threadIdx.x;
    const float* base = out + NT;
    const int* count    = (const int*)base + SCR_COUNT;
    const int* flaglist = (const int*)base + SCR_LIST;
    int cnt = *count;
    if (cnt > LISTCAP) cnt = LISTCAP;

    for (int it = blockIdx.x; it < cnt; it += gridDim.x) {
        const int row = flaglist[it];
        const int n = row >> 13, t = row & (T_DIM - 1);
        if (tid < C_DIM)
            xv[tid] = x[((size_t)n * C_DIM + tid) * T_DIM + t];
        __syncthreads();
        if (tid == 0) sxxs = np_sumsq64(xv);
        __syncthreads();
        const float xx = sxxs;

        float bv = __builtin_inff();
        int   bb = 0x7fffffff;
        for (int b = tid; b < KB; b += 256) {
            const float* kr = k + (size_t)b * C_DIM;
            float dot = 0.f;
            #pragma unroll
            for (int c = 0; c < C_DIM; ++c)
                dot = fmaf(xv[c], kr[c], dot);
            float kk = base[SCR_KK + b];
            float d  = __fadd_rn(__fsub_rn(xx, __fadd_rn(dot, dot)), kk);
            if (d < bv) { bv = d; bb = b; }
        }
        #pragma unroll
        for (int off = 1; off <= 32; off <<= 1) {
            float ov = __shfl_xor(bv, off, 64);
            int   ob = __shfl_xor(bb, off, 64);
            if (ov < bv || (ov == bv && ob < bb)) { bv = ov; bb = ob; }
        }
        const int wid = tid >> 6, lane = tid & 63;
        if (lane == 0) { redv[wid] = bv; redb[wid] = bb; }
        __syncthreads();
        if (tid == 0) {
            float fv = redv[0]; int fb = redb[0];
            #pragma unroll
            for (int wq = 1; wq < 4; ++wq) {
                if (redv[wq] < fv || (redv[wq] == fv && redb[wq] < fb)) {
                    fv = redv[wq]; fb = redb[wq];
                }
            }
            out[row] = (float)fb;
        }
        __syncthreads();
    }
}

// ------------------------------------------------------------- finalize ----
__global__ __launch_bounds__(256) void finalize_kernel(float* __restrict__ out) {
    const float* partials = (out + NT) + SCR_PART;
    const int tid = threadIdx.x;
    double vals[5] = {0, 0, 0, 0, 0};
    for (int i = tid; i < NBLK; i += 256)
        #pragma unroll
        for (int q = 0; q < 5; ++q) vals[q] += (double)partials[(size_t)i * 8 + q];
    #pragma unroll
    for (int off = 1; off <= 32; off <<= 1)
        #pragma unroll
        for (int q = 0; q < 5; ++q) vals[q] += __shfl_xor(vals[q], off, 64);
    __shared__ double sred[4][5];
    const int wid = tid >> 6, lane = tid & 63;
    if (lane == 0)
        for (int q = 0; q < 5; ++q) sred[wid][q] = vals[q];
    __syncthreads();
    if (tid == 0) {
        double cm  = sred[0][0] + sred[1][0] + sred[2][0] + sred[3][0];
        double fs  = sred[0][1] + sred[1][1] + sred[2][1] + sred[3][1];
        double ms  = sred[0][2] + sred[1][2] + sred[2][2] + sred[3][2];
        double sx  = sred[0][3] + sred[1][3] + sred[2][3] + sred[3][3];
        double sxx = sred[0][4] + sred[1][4] + sred[2][4] + sred[3][4];
        double sz  = (double)TOTX;
        out[NT + TOTX + 0] = (float)(cm / (ms * (double)C_DIM));
        out[NT + TOTX + 1] = (float)(fs / (double)NT);
        out[NT + TOTX + 2] = (float)sqrt(fmax(0.0, (sxx - sx * sx / sz) / sz));
    }
}

// --------------------------------------------------------------------- x_d ----
// Runs LAST: overwrites the scratch region with real x_d values.
__global__ __launch_bounds__(256) void xd_kernel(const float* __restrict__ mask,
                                                 const float* __restrict__ k,
                                                 float* __restrict__ out) {
    const int row = blockIdx.x * 256 + threadIdx.x;
    const int n = row >> 13, t = row & (T_DIM - 1);
    const int b = (int)out[row];
    const float m = mask[row];
    const float* kr = k + (size_t)b * C_DIM;
    float* xd = out + NT;
    #pragma unroll
    for (int c = 0; c < C_DIM; ++c)
        xd[((size_t)n * C_DIM + c) * T_DIM + t] = kr[c] * m;
}

// ----------------------------------------------------------------- launch ----
extern "C" void kernel_launch(void* const* d_in, const int* in_sizes, int n_in,
                              void* d_out, int out_size, void* d_ws, size_t ws_size,
                              hipStream_t stream) {
    (void)in_sizes; (void)n_in; (void)out_size; (void)d_ws; (void)ws_size;
    const float* x    = (const float*)d_in[0];
    const float* mask = (const float*)d_in[1];
    const float* k    = (const float*)d_in[2];
    float* out = (float*)d_out;

    kprep_kernel<<<KB / 256, 256, 0, stream>>>(k, out);
    argmin_kernel<<<NBLK, 256, 0, stream>>>(x, mask, out);
    fixup_kernel<<<1024, 256, 0, stream>>>(x, k, out);
    finalize_kernel<<<1, 256, 0, stream>>>(out);
    xd_kernel<<<NT / 256, 256, 0, stream>>>(mask, k, out);
}

// Round 14
// 743.240 us; speedup vs baseline: 4.2742x; 4.2742x over previous
//
#include <hip/hip_runtime.h>

#define T_DIM 8192
#define N_DIM 8
#define C_DIM 64
#define KB    2048
#define NT    (N_DIM * T_DIM)        // 65536 rows
#define TOTX  ((size_t)NT * C_DIM)   // 4194304 elements
#define NBLK  1024                   // argmin blocks (64 rows each)
#define LISTCAP 65536
#define TAU   0.04f

// Scratch inside out's x_d region (out + NT), overwritten LAST by xd_kernel.
// Offsets in FLOAT units from out+NT:
#define SCR_COUNT 0                   // int
#define SCR_LIST  16                  // int[65536]      -> ends 65552
#define SCR_PART  65792               // float[1024][8]  -> ends 73984
#define SCR_KNS   74240               // float[2048]     -> ends 76288
#define SCR_KK    76544               // float[2048]     -> ends 78592
#define SCR_K     81920               // f16x8 khi[16][8][128] (256 KB) -> 147456

typedef _Float16 half_t;
typedef _Float16 f16x8 __attribute__((ext_vector_type(8)));
typedef float    f32x16 __attribute__((ext_vector_type(16)));

// numpy pairwise sum (n=64) of squares (np-exact, fixup path).
__device__ __forceinline__ float np_sumsq64(const float* __restrict__ a) {
    float r[8];
    #pragma unroll
    for (int j = 0; j < 8; ++j) r[j] = __fmul_rn(a[j], a[j]);
    #pragma unroll
    for (int i = 8; i < 64; i += 8)
        #pragma unroll
        for (int j = 0; j < 8; ++j)
            r[j] = __fadd_rn(r[j], __fmul_rn(a[i + j], a[i + j]));
    return __fadd_rn(__fadd_rn(__fadd_rn(r[0], r[1]), __fadd_rn(r[2], r[3])),
                     __fadd_rn(__fadd_rn(r[4], r[5]), __fadd_rn(r[6], r[7])));
}

// ------------------------------------------------------------------ k prep ----
// khi[ch][slot][bin127] = -2*f16(k). kns = seq-fma ||k||^2 (filter offset);
// kk = np-exact ||k||^2 (fixup).
__global__ __launch_bounds__(256) void kprep_kernel(const float* __restrict__ k,
                                                    float* __restrict__ out) {
    float* base = out + NT;
    const int bin = blockIdx.x * 256 + threadIdx.x;   // grid 8 -> 2048
    if (bin == 0) ((int*)base)[SCR_COUNT] = 0;

    float kv[64];
    #pragma unroll
    for (int i = 0; i < 16; ++i)
        *(float4*)&kv[i * 4] = *(const float4*)(k + (size_t)bin * 64 + i * 4);

    float kn = 0.f;
    #pragma unroll
    for (int c = 0; c < 64; ++c) kn = fmaf(kv[c], kv[c], kn);
    base[SCR_KNS + bin] = kn;
    base[SCR_KK + bin]  = np_sumsq64(kv);

    f16x8* khi = (f16x8*)(base + SCR_K);
    const int ch = bin >> 7, b127 = bin & 127;
    #pragma unroll
    for (int slot = 0; slot < 8; ++slot) {
        f16x8 h8;
        #pragma unroll
        for (int e = 0; e < 8; ++e)
            h8[e] = (half_t)(-2.f * (float)((half_t)kv[slot * 8 + e]));
        khi[(size_t)ch * 1024 + slot * 128 + b127] = h8;
    }
}

// ------------------------------------------------------------------ argmin ----
// Grid 1024, block = 64 rows x 4 waves: wave w -> (rg=w>>1 rows, hb=w&1 bins).
// hi-only filter (4 MFMA/tile), reg-direct B loads, no k-loop barriers.
__global__ __launch_bounds__(256, 3) void argmin_kernel(const float* __restrict__ x,
                                                        const float* __restrict__ mask,
                                                        float* __restrict__ out) {
    __shared__ __align__(16) f16x8 xhi_s[512];   // [8 slots][64 rows]
    __shared__ float kns_s[2048];
    __shared__ float psx[4][64], psxx[4][64];
    __shared__ float wres[2][64][3];

    float* base = out + NT;
    const int tid = threadIdx.x;
    const int l   = tid & 63, w = tid >> 6;
    const int col = l & 31, kg = l >> 5;
    const int rg  = w >> 1, hb = w & 1;
    const int r0  = blockIdx.x * 64;
    const int n   = r0 >> 13;
    const int t0  = r0 & (T_DIM - 1);

    #pragma unroll
    for (int i = 0; i < 8; ++i)
        kns_s[i * 256 + tid] = base[SCR_KNS + i * 256 + tid];

    // prologue: x load + f16-hi split + row stats (thread: row=tid&63, 2 slots)
    {
        const int row = tid & 63, sp = tid >> 6;
        float sx = 0.f, sxx = 0.f;
        #pragma unroll
        for (int ss = 0; ss < 2; ++ss) {
            const int slot = sp * 2 + ss;
            f16x8 h8;
            #pragma unroll
            for (int e = 0; e < 8; ++e) {
                float v = x[((size_t)n * C_DIM + slot * 8 + e) * T_DIM + t0 + row];
                h8[e] = (half_t)v;
                sx += v; sxx = fmaf(v, v, sxx);
            }
            xhi_s[slot * 64 + row] = h8;
        }
        psx[sp][row]  = sx;
        psxx[sp][row] = sxx;
    }
    __syncthreads();

    // A fragments: rows rg*32 + col, K=64 over 4 k-steps
    f16x8 a0 = xhi_s[(0 + kg) * 64 + rg * 32 + col];
    f16x8 a1 = xhi_s[(2 + kg) * 64 + rg * 32 + col];
    f16x8 a2 = xhi_s[(4 + kg) * 64 + rg * 32 + col];
    f16x8 a3 = xhi_s[(6 + kg) * 64 + rg * 32 + col];

    // per-wave k base (bin half hb): tile t local, offset (t>>2)*1024+(t&3)*32
    const f16x8* kfw = (const f16x8*)(base + SCR_K)
                       + (size_t)hb * 8192 + kg * 128 + col;

    f32x16 zacc;
    #pragma unroll
    for (int r = 0; r < 16; ++r) zacc[r] = 0.f;

    float bestv[16], best2v[16];
    int   bestb[16];
    #pragma unroll
    for (int r = 0; r < 16; ++r) {
        bestv[r] = __builtin_inff(); best2v[r] = __builtin_inff(); bestb[r] = 0;
    }

    f16x8 bA[4], bB[4], bC[4], bD[4];

#define LOADT(t, BH)                                                \
    {                                                               \
        const f16x8* p = kfw + (((t) >> 2) * 1024 + ((t) & 3) * 32);\
        BH[0] = p[0]; BH[1] = p[256]; BH[2] = p[512]; BH[3] = p[768]; \
    }

#define COMPT(t, BH)                                                         \
    {                                                                        \
        const float kn = kns_s[hb * 1024 + (t) * 32 + col];                  \
        __builtin_amdgcn_s_setprio(1);                                       \
        f32x16 acc = __builtin_amdgcn_mfma_f32_32x32x16_f16(a0, BH[0], zacc, 0, 0, 0); \
        acc = __builtin_amdgcn_mfma_f32_32x32x16_f16(a1, BH[1], acc, 0, 0, 0); \
        acc = __builtin_amdgcn_mfma_f32_32x32x16_f16(a2, BH[2], acc, 0, 0, 0); \
        acc = __builtin_amdgcn_mfma_f32_32x32x16_f16(a3, BH[3], acc, 0, 0, 0); \
        __builtin_amdgcn_s_setprio(0);                                       \
        const int binf = hb * 1024 + (t) * 32 + col;                         \
        _Pragma("unroll")                                                    \
        for (int r = 0; r < 16; ++r) {                                       \
            float sv = acc[r] + kn;                                          \
            best2v[r] = fminf(best2v[r], fmaxf(sv, bestv[r]));               \
            if (sv < bestv[r]) { bestv[r] = sv; bestb[r] = binf; }           \
        }                                                                    \
    }

    LOADT(0, bA); LOADT(1, bB);
    #pragma unroll 1
    for (int t = 0; t < 24; t += 4) {
        LOADT(t + 2, bC); COMPT(t,     bA);
        LOADT(t + 3, bD); COMPT(t + 1, bB);
        LOADT(t + 4, bA); COMPT(t + 2, bC);
        LOADT(t + 5, bB); COMPT(t + 3, bD);
    }
    LOADT(26, bC); COMPT(24, bA);
    LOADT(27, bD); COMPT(25, bB);
    LOADT(28, bA); COMPT(26, bC);
    LOADT(29, bB); COMPT(27, bD);
    LOADT(30, bC); COMPT(28, bA);
    LOADT(31, bD); COMPT(29, bB);
    COMPT(30, bC);
    COMPT(31, bD);
#undef LOADT
#undef COMPT

    // merge across the 32 column-lanes of each half, tracking 2nd-best
    #pragma unroll
    for (int off = 1; off <= 16; off <<= 1) {
        #pragma unroll
        for (int r = 0; r < 16; ++r) {
            float ov = __shfl_xor(bestv[r], off, 64);
            int   ob = __shfl_xor(bestb[r], off, 64);
            float o2 = __shfl_xor(best2v[r], off, 64);
            float mx = fmaxf(bestv[r], ov);
            best2v[r] = fminf(fminf(best2v[r], o2), mx);
            if (ov < bestv[r] || (ov == bestv[r] && ob < bestb[r])) {
                bestv[r] = ov; bestb[r] = ob;
            }
        }
    }

    // stash per-(bin-half, row) results
    if (col == 0) {
        #pragma unroll
        for (int r = 0; r < 16; ++r) {
            const int row_loc = rg * 32 + 4 * kg + (r & 3) + 8 * (r >> 2);
            wres[hb][row_loc][0] = bestv[r];
            wres[hb][row_loc][1] = best2v[r];
            wres[hb][row_loc][2] = __int_as_float(bestb[r]);
        }
    }
    __syncthreads();

    // final merge: threads 0..63 (wave 0) own one row each
    if (tid < 64) {
        const int row = tid;
        const float v0 = wres[0][row][0], v1 = wres[1][row][0];
        float bv = v0; int bb = __float_as_int(wres[0][row][2]);
        if (v1 < bv) { bv = v1; bb = __float_as_int(wres[1][row][2]); }
        const float b2 = fminf(fminf(wres[0][row][1], wres[1][row][1]),
                               fmaxf(v0, v1));
        out[r0 + row] = (float)bb;
        if (b2 - bv < TAU) {
            int idx = atomicAdd((int*)base + SCR_COUNT, 1);
            if (idx < LISTCAP) ((int*)base + SCR_LIST)[idx] = r0 + row;
        }
        float sx = 0.f, sxx = 0.f;
        #pragma unroll
        for (int sp = 0; sp < 4; ++sp) { sx += psx[sp][row]; sxx += psxx[sp][row]; }
        const float m  = mask[r0 + row];
        const float d2 = sxx + bv;
        float vals[5] = { m * d2, d2, m, sx, sxx };
        #pragma unroll
        for (int off = 1; off <= 32; off <<= 1)
            #pragma unroll
            for (int q = 0; q < 5; ++q) vals[q] += __shfl_xor(vals[q], off, 64);
        if (tid == 0) {
            float* partials = base + SCR_PART;
            #pragma unroll
            for (int q = 0; q < 5; ++q)
                partials[(size_t)blockIdx.x * 8 + q] = vals[q];
        }
    }
}

// ------------------------------------------------------------------ fixup ----
// Batched np-f32-exact recompute: 32 flagged rows per batch, k streamed once
// per batch (broadcast across the 32 row-lanes), 8 threads per row.
__global__ __launch_bounds__(256) void fixup_kernel(const float* __restrict__ x,
                                                    const float* __restrict__ k,
                                                    float* __restrict__ out) {
    __shared__ float xs[32][65];
    __shared__ float sxx_s[32];
    __shared__ float redv[256];
    __shared__ int   redb[256];

    const int tid = threadIdx.x;
    const float* base = out + NT;
    const int* count    = (const int*)base + SCR_COUNT;
    const int* flaglist = (const int*)base + SCR_LIST;
    const float* kk     = base + SCR_KK;
    int cnt = *count;
    if (cnt > LISTCAP) cnt = LISTCAP;

    const int rloc = tid & 31, part = tid >> 5;

    for (int bi = blockIdx.x; bi * 32 < cnt; bi += gridDim.x) {
        int li = bi * 32 + rloc;
        if (li >= cnt) li = bi * 32;                 // clamp (duplicate row ok)
        const int row = flaglist[li];
        const int n = row >> 13, t = row & (T_DIM - 1);
        #pragma unroll
        for (int e = 0; e < 8; ++e)
            xs[rloc][part * 8 + e] = x[((size_t)n * C_DIM + part * 8 + e) * T_DIM + t];
        __syncthreads();
        if (tid < 32) sxx_s[tid] = np_sumsq64(&xs[tid][0]);
        __syncthreads();

        float xr[64];
        #pragma unroll
        for (int c = 0; c < 64; ++c) xr[c] = xs[rloc][c];
        const float xx = sxx_s[rloc];

        float bv = __builtin_inff();
        int   bb = 0x7fffffff;
        #pragma unroll 1
        for (int j = 0; j < 128; ++j) {
            const int b0 = part + 16 * j;
            const int b1 = b0 + 8;
            const float* k0 = k + (size_t)b0 * 64;
            const float* k1 = k + (size_t)b1 * 64;
            float d0 = 0.f, d1 = 0.f;
            #pragma unroll
            for (int c = 0; c < 64; ++c) {
                d0 = fmaf(xr[c], k0[c], d0);
                d1 = fmaf(xr[c], k1[c], d1);
            }
            float s0 = __fadd_rn(__fsub_rn(xx, __fadd_rn(d0, d0)), kk[b0]);
            float s1 = __fadd_rn(__fsub_rn(xx, __fadd_rn(d1, d1)), kk[b1]);
            if (s0 < bv || (s0 == bv && b0 < bb)) { bv = s0; bb = b0; }
            if (s1 < bv || (s1 == bv && b1 < bb)) { bv = s1; bb = b1; }
        }
        redv[tid] = bv; redb[tid] = bb;
        __syncthreads();
        if (tid < 32) {
            float fv = redv[tid]; int fb = redb[tid];
            #pragma unroll
            for (int p = 1; p < 8; ++p) {
                float ov = redv[p * 32 + tid];
                int   ob = redb[p * 32 + tid];
                if (ov < fv || (ov == fv && ob < fb)) { fv = ov; fb = ob; }
            }
            if (bi * 32 + tid < cnt)
                out[flaglist[bi * 32 + tid]] = (float)fb;
        }
        __syncthreads();
    }
}

// ------------------------------------------------------------- finalize ----
__global__ __launch_bounds__(256) void finalize_kernel(float* __restrict__ out) {
    const float* partials = (out + NT) + SCR_PART;
    const int tid = threadIdx.x;
    double vals[5] = {0, 0, 0, 0, 0};
    for (int i = tid; i < NBLK; i += 256)
        #pragma unroll
        for (int q = 0; q < 5; ++q) vals[q] += (double)partials[(size_t)i * 8 + q];
    #pragma unroll
    for (int off = 1; off <= 32; off <<= 1)
        #pragma unroll
        for (int q = 0; q < 5; ++q) vals[q] += __shfl_xor(vals[q], off, 64);
    __shared__ double sred[4][5];
    const int wid = tid >> 6, lane = tid & 63;
    if (lane == 0)
        for (int q = 0; q < 5; ++q) sred[wid][q] = vals[q];
    __syncthreads();
    if (tid == 0) {
        double cm  = sred[0][0] + sred[1][0] + sred[2][0] + sred[3][0];
        double fs  = sred[0][1] + sred[1][1] + sred[2][1] + sred[3][1];
        double ms  = sred[0][2] + sred[1][2] + sred[2][2] + sred[3][2];
        double sx  = sred[0][3] + sred[1][3] + sred[2][3] + sred[3][3];
        double sxx = sred[0][4] + sred[1][4] + sred[2][4] + sred[3][4];
        double sz  = (double)TOTX;
        out[NT + TOTX + 0] = (float)(cm / (ms * (double)C_DIM));
        out[NT + TOTX + 1] = (float)(fs / (double)NT);
        out[NT + TOTX + 2] = (float)sqrt(fmax(0.0, (sxx - sx * sx / sz) / sz));
    }
}

// --------------------------------------------------------------------- x_d ----
// Runs LAST: overwrites the scratch region with real x_d values.
__global__ __launch_bounds__(256) void xd_kernel(const float* __restrict__ mask,
                                                 const float* __restrict__ k,
                                                 float* __restrict__ out) {
    const int row = blockIdx.x * 256 + threadIdx.x;
    const int n = row >> 13, t = row & (T_DIM - 1);
    const int b = (int)out[row];
    const float m = mask[row];
    const float* kr = k + (size_t)b * C_DIM;
    float* xd = out + NT;
    #pragma unroll
    for (int c = 0; c < C_DIM; ++c)
        xd[((size_t)n * C_DIM + c) * T_DIM + t] = kr[c] * m;
}

// ----------------------------------------------------------------- launch ----
extern "C" void kernel_launch(void* const* d_in, const int* in_sizes, int n_in,
                              void* d_out, int out_size, void* d_ws, size_t ws_size,
                              hipStream_t stream) {
    (void)in_sizes; (void)n_in; (void)out_size; (void)d_ws; (void)ws_size;
    const float* x    = (const float*)d_in[0];
    const float* mask = (const float*)d_in[1];
    const float* k    = (const float*)d_in[2];
    float* out = (float*)d_out;

    kprep_kernel<<<KB / 256, 256, 0, stream>>>(k, out);
    argmin_kernel<<<NBLK, 256, 0, stream>>>(x, mask, out);
    fixup_kernel<<<1024, 256, 0, stream>>>(x, k, out);
    finalize_kernel<<<1, 256, 0, stream>>>(out);
    xd_kernel<<<NT / 256, 256, 0, stream>>>(mask, k, out);
}

// Round 15
// 253.951 us; speedup vs baseline: 12.5095x; 2.9267x over previous
//
#include <hip/hip_runtime.h>

#define T_DIM 8192
#define N_DIM 8
#define C_DIM 64
#define KB    2048
#define NT    (N_DIM * T_DIM)        // 65536 rows
#define TOTX  ((size_t)NT * C_DIM)   // 4194304 elements
#define NBLK  1024                   // argmin blocks (64 rows each)
#define LISTCAP 65536
#define TAU   0.04f

// Scratch inside out's x_d region (out + NT), overwritten LAST by xd_kernel.
// Offsets in FLOAT units from out+NT:
#define SCR_COUNT 0                   // int
#define SCR_LIST  16                  // int[65536]      -> ends 65552
#define SCR_PART  65792               // float[1024][8]  -> ends 73984
#define SCR_KNS   74240               // float[2048]     -> ends 76288
#define SCR_KK    76544               // float[2048]     -> ends 78592
#define SCR_K     81920               // f16x8 khi[16][8][128] (256 KB) -> 147456

typedef _Float16 half_t;
typedef _Float16 f16x8 __attribute__((ext_vector_type(8)));
typedef float    f32x16 __attribute__((ext_vector_type(16)));

// numpy pairwise sum (n=64) of squares (np-exact, fixup path).
__device__ __forceinline__ float np_sumsq64(const float* __restrict__ a) {
    float r[8];
    #pragma unroll
    for (int j = 0; j < 8; ++j) r[j] = __fmul_rn(a[j], a[j]);
    #pragma unroll
    for (int i = 8; i < 64; i += 8)
        #pragma unroll
        for (int j = 0; j < 8; ++j)
            r[j] = __fadd_rn(r[j], __fmul_rn(a[i + j], a[i + j]));
    return __fadd_rn(__fadd_rn(__fadd_rn(r[0], r[1]), __fadd_rn(r[2], r[3])),
                     __fadd_rn(__fadd_rn(r[4], r[5]), __fadd_rn(r[6], r[7])));
}

// ------------------------------------------------------------------ k prep ----
// khi[ch][slot][bin127] = -2*f16(k). kns = seq-fma ||k||^2 (filter offset);
// kk = np-exact ||k||^2 (fixup).
__global__ __launch_bounds__(256) void kprep_kernel(const float* __restrict__ k,
                                                    float* __restrict__ out) {
    float* base = out + NT;
    const int bin = blockIdx.x * 256 + threadIdx.x;   // grid 8 -> 2048
    if (bin == 0) ((int*)base)[SCR_COUNT] = 0;

    float kv[64];
    #pragma unroll
    for (int i = 0; i < 16; ++i)
        *(float4*)&kv[i * 4] = *(const float4*)(k + (size_t)bin * 64 + i * 4);

    float kn = 0.f;
    #pragma unroll
    for (int c = 0; c < 64; ++c) kn = fmaf(kv[c], kv[c], kn);
    base[SCR_KNS + bin] = kn;
    base[SCR_KK + bin]  = np_sumsq64(kv);

    f16x8* khi = (f16x8*)(base + SCR_K);
    const int ch = bin >> 7, b127 = bin & 127;
    #pragma unroll
    for (int slot = 0; slot < 8; ++slot) {
        f16x8 h8;
        #pragma unroll
        for (int e = 0; e < 8; ++e)
            h8[e] = (half_t)(-2.f * (float)((half_t)kv[slot * 8 + e]));
        khi[(size_t)ch * 1024 + slot * 128 + b127] = h8;
    }
}

// ------------------------------------------------------------------ argmin ----
// Grid 1024, block = 64 rows x 4 waves: wave w -> (rg=w>>1 rows, hb=w&1 bins).
// hi-only filter (4 MFMA/tile), reg-direct B loads, no k-loop barriers.
// launch_bounds (256,2): register ceiling 256 — NO forced-occupancy spills.
__global__ __launch_bounds__(256, 2) void argmin_kernel(const float* __restrict__ x,
                                                        const float* __restrict__ mask,
                                                        float* __restrict__ out) {
    __shared__ __align__(16) f16x8 xhi_s[512];   // [8 slots][64 rows]
    __shared__ float kns_s[2048];
    __shared__ float psx[4][64], psxx[4][64];
    __shared__ float wres[2][64][3];

    float* base = out + NT;
    const int tid = threadIdx.x;
    const int l   = tid & 63, w = tid >> 6;
    const int col = l & 31, kg = l >> 5;
    const int rg  = w >> 1, hb = w & 1;
    const int r0  = blockIdx.x * 64;
    const int n   = r0 >> 13;
    const int t0  = r0 & (T_DIM - 1);

    #pragma unroll
    for (int i = 0; i < 8; ++i)
        kns_s[i * 256 + tid] = base[SCR_KNS + i * 256 + tid];

    // prologue: x load + f16-hi split + row stats (thread: row=tid&63, 2 slots)
    {
        const int row = tid & 63, sp = tid >> 6;
        float sx = 0.f, sxx = 0.f;
        #pragma unroll
        for (int ss = 0; ss < 2; ++ss) {
            const int slot = sp * 2 + ss;
            f16x8 h8;
            #pragma unroll
            for (int e = 0; e < 8; ++e) {
                float v = x[((size_t)n * C_DIM + slot * 8 + e) * T_DIM + t0 + row];
                h8[e] = (half_t)v;
                sx += v; sxx = fmaf(v, v, sxx);
            }
            xhi_s[slot * 64 + row] = h8;
        }
        psx[sp][row]  = sx;
        psxx[sp][row] = sxx;
    }
    __syncthreads();

    // A fragments: rows rg*32 + col, K=64 over 4 k-steps
    f16x8 a0 = xhi_s[(0 + kg) * 64 + rg * 32 + col];
    f16x8 a1 = xhi_s[(2 + kg) * 64 + rg * 32 + col];
    f16x8 a2 = xhi_s[(4 + kg) * 64 + rg * 32 + col];
    f16x8 a3 = xhi_s[(6 + kg) * 64 + rg * 32 + col];

    // per-wave k base (bin half hb): tile t local, offset (t>>2)*1024+(t&3)*32
    const f16x8* kfw = (const f16x8*)(base + SCR_K)
                       + (size_t)hb * 8192 + kg * 128 + col;

    f32x16 zacc;
    #pragma unroll
    for (int r = 0; r < 16; ++r) zacc[r] = 0.f;

    float bestv[16], best2v[16];
    int   bestb[16];
    #pragma unroll
    for (int r = 0; r < 16; ++r) {
        bestv[r] = __builtin_inff(); best2v[r] = __builtin_inff(); bestb[r] = 0;
    }

    f16x8 bA[4], bB[4], bC[4], bD[4];

#define LOADT(t, BH)                                                \
    {                                                               \
        const f16x8* p = kfw + (((t) >> 2) * 1024 + ((t) & 3) * 32);\
        BH[0] = p[0]; BH[1] = p[256]; BH[2] = p[512]; BH[3] = p[768]; \
    }

#define COMPT(t, BH)                                                         \
    {                                                                        \
        const float kn = kns_s[hb * 1024 + (t) * 32 + col];                  \
        __builtin_amdgcn_s_setprio(1);                                       \
        f32x16 acc = __builtin_amdgcn_mfma_f32_32x32x16_f16(a0, BH[0], zacc, 0, 0, 0); \
        acc = __builtin_amdgcn_mfma_f32_32x32x16_f16(a1, BH[1], acc, 0, 0, 0); \
        acc = __builtin_amdgcn_mfma_f32_32x32x16_f16(a2, BH[2], acc, 0, 0, 0); \
        acc = __builtin_amdgcn_mfma_f32_32x32x16_f16(a3, BH[3], acc, 0, 0, 0); \
        __builtin_amdgcn_s_setprio(0);                                       \
        const int binf = hb * 1024 + (t) * 32 + col;                         \
        _Pragma("unroll")                                                    \
        for (int r = 0; r < 16; ++r) {                                       \
            float sv = acc[r] + kn;                                          \
            best2v[r] = fminf(best2v[r], fmaxf(sv, bestv[r]));               \
            if (sv < bestv[r]) { bestv[r] = sv; bestb[r] = binf; }           \
        }                                                                    \
    }

    LOADT(0, bA); LOADT(1, bB);
    #pragma unroll 1
    for (int t = 0; t < 24; t += 4) {
        LOADT(t + 2, bC); COMPT(t,     bA);
        LOADT(t + 3, bD); COMPT(t + 1, bB);
        LOADT(t + 4, bA); COMPT(t + 2, bC);
        LOADT(t + 5, bB); COMPT(t + 3, bD);
    }
    LOADT(26, bC); COMPT(24, bA);
    LOADT(27, bD); COMPT(25, bB);
    LOADT(28, bA); COMPT(26, bC);
    LOADT(29, bB); COMPT(27, bD);
    LOADT(30, bC); COMPT(28, bA);
    LOADT(31, bD); COMPT(29, bB);
    COMPT(30, bC);
    COMPT(31, bD);
#undef LOADT
#undef COMPT

    // merge across the 32 column-lanes of each half, tracking 2nd-best
    #pragma unroll
    for (int off = 1; off <= 16; off <<= 1) {
        #pragma unroll
        for (int r = 0; r < 16; ++r) {
            float ov = __shfl_xor(bestv[r], off, 64);
            int   ob = __shfl_xor(bestb[r], off, 64);
            float o2 = __shfl_xor(best2v[r], off, 64);
            float mx = fmaxf(bestv[r], ov);
            best2v[r] = fminf(fminf(best2v[r], o2), mx);
            if (ov < bestv[r] || (ov == bestv[r] && ob < bestb[r])) {
                bestv[r] = ov; bestb[r] = ob;
            }
        }
    }

    // stash per-(bin-half, row) results
    if (col == 0) {
        #pragma unroll
        for (int r = 0; r < 16; ++r) {
            const int row_loc = rg * 32 + 4 * kg + (r & 3) + 8 * (r >> 2);
            wres[hb][row_loc][0] = bestv[r];
            wres[hb][row_loc][1] = best2v[r];
            wres[hb][row_loc][2] = __int_as_float(bestb[r]);
        }
    }
    __syncthreads();

    // final merge: threads 0..63 (wave 0) own one row each
    if (tid < 64) {
        const int row = tid;
        const float v0 = wres[0][row][0], v1 = wres[1][row][0];
        float bv = v0; int bb = __float_as_int(wres[0][row][2]);
        if (v1 < bv) { bv = v1; bb = __float_as_int(wres[1][row][2]); }
        const float b2 = fminf(fminf(wres[0][row][1], wres[1][row][1]),
                               fmaxf(v0, v1));
        out[r0 + row] = (float)bb;
        if (b2 - bv < TAU) {
            int idx = atomicAdd((int*)base + SCR_COUNT, 1);
            if (idx < LISTCAP) ((int*)base + SCR_LIST)[idx] = r0 + row;
        }
        float sx = 0.f, sxx = 0.f;
        #pragma unroll
        for (int sp = 0; sp < 4; ++sp) { sx += psx[sp][row]; sxx += psxx[sp][row]; }
        const float m  = mask[r0 + row];
        const float d2 = sxx + bv;
        float vals[5] = { m * d2, d2, m, sx, sxx };
        #pragma unroll
        for (int off = 1; off <= 32; off <<= 1)
            #pragma unroll
            for (int q = 0; q < 5; ++q) vals[q] += __shfl_xor(vals[q], off, 64);
        if (tid == 0) {
            float* partials = base + SCR_PART;
            #pragma unroll
            for (int q = 0; q < 5; ++q)
                partials[(size_t)blockIdx.x * 8 + q] = vals[q];
        }
    }
}

// ------------------------------------------------------------------ fixup ----
// Batched np-f32-exact recompute: 32 flagged rows per batch, k streamed once
// per batch (broadcast across the 32 row-lanes), 8 threads per row.
__global__ __launch_bounds__(256) void fixup_kernel(const float* __restrict__ x,
                                                    const float* __restrict__ k,
                                                    float* __restrict__ out) {
    __shared__ float xs[32][65];
    __shared__ float sxx_s[32];
    __shared__ float redv[256];
    __shared__ int   redb[256];

    const int tid = threadIdx.x;
    const float* base = out + NT;
    const int* count    = (const int*)base + SCR_COUNT;
    const int* flaglist = (const int*)base + SCR_LIST;
    const float* kk     = base + SCR_KK;
    int cnt = *count;
    if (cnt > LISTCAP) cnt = LISTCAP;

    const int rloc = tid & 31, part = tid >> 5;

    for (int bi = blockIdx.x; bi * 32 < cnt; bi += gridDim.x) {
        int li = bi * 32 + rloc;
        if (li >= cnt) li = bi * 32;                 // clamp (duplicate row ok)
        const int row = flaglist[li];
        const int n = row >> 13, t = row & (T_DIM - 1);
        #pragma unroll
        for (int e = 0; e < 8; ++e)
            xs[rloc][part * 8 + e] = x[((size_t)n * C_DIM + part * 8 + e) * T_DIM + t];
        __syncthreads();
        if (tid < 32) sxx_s[tid] = np_sumsq64(&xs[tid][0]);
        __syncthreads();

        float xr[64];
        #pragma unroll
        for (int c = 0; c < 64; ++c) xr[c] = xs[rloc][c];
        const float xx = sxx_s[rloc];

        float bv = __builtin_inff();
        int   bb = 0x7fffffff;
        #pragma unroll 1
        for (int j = 0; j < 128; ++j) {
            const int b0 = part + 16 * j;
            const int b1 = b0 + 8;
            const float* k0 = k + (size_t)b0 * 64;
            const float* k1 = k + (size_t)b1 * 64;
            float d0 = 0.f, d1 = 0.f;
            #pragma unroll
            for (int c = 0; c < 64; ++c) {
                d0 = fmaf(xr[c], k0[c], d0);
                d1 = fmaf(xr[c], k1[c], d1);
            }
            float s0 = __fadd_rn(__fsub_rn(xx, __fadd_rn(d0, d0)), kk[b0]);
            float s1 = __fadd_rn(__fsub_rn(xx, __fadd_rn(d1, d1)), kk[b1]);
            if (s0 < bv || (s0 == bv && b0 < bb)) { bv = s0; bb = b0; }
            if (s1 < bv || (s1 == bv && b1 < bb)) { bv = s1; bb = b1; }
        }
        redv[tid] = bv; redb[tid] = bb;
        __syncthreads();
        if (tid < 32) {
            float fv = redv[tid]; int fb = redb[tid];
            #pragma unroll
            for (int p = 1; p < 8; ++p) {
                float ov = redv[p * 32 + tid];
                int   ob = redb[p * 32 + tid];
                if (ov < fv || (ov == fv && ob < fb)) { fv = ov; fb = ob; }
            }
            if (bi * 32 + tid < cnt)
                out[flaglist[bi * 32 + tid]] = (float)fb;
        }
        __syncthreads();
    }
}

// ------------------------------------------------------------- finalize ----
__global__ __launch_bounds__(256) void finalize_kernel(float* __restrict__ out) {
    const float* partials = (out + NT) + SCR_PART;
    const int tid = threadIdx.x;
    double vals[5] = {0, 0, 0, 0, 0};
    for (int i = tid; i < NBLK; i += 256)
        #pragma unroll
        for (int q = 0; q < 5; ++q) vals[q] += (double)partials[(size_t)i * 8 + q];
    #pragma unroll
    for (int off = 1; off <= 32; off <<= 1)
        #pragma unroll
        for (int q = 0; q < 5; ++q) vals[q] += __shfl_xor(vals[q], off, 64);
    __shared__ double sred[4][5];
    const int wid = tid >> 6, lane = tid & 63;
    if (lane == 0)
        for (int q = 0; q < 5; ++q) sred[wid][q] = vals[q];
    __syncthreads();
    if (tid == 0) {
        double cm  = sred[0][0] + sred[1][0] + sred[2][0] + sred[3][0];
        double fs  = sred[0][1] + sred[1][1] + sred[2][1] + sred[3][1];
        double ms  = sred[0][2] + sred[1][2] + sred[2][2] + sred[3][2];
        double sx  = sred[0][3] + sred[1][3] + sred[2][3] + sred[3][3];
        double sxx = sred[0][4] + sred[1][4] + sred[2][4] + sred[3][4];
        double sz  = (double)TOTX;
        out[NT + TOTX + 0] = (float)(cm / (ms * (double)C_DIM));
        out[NT + TOTX + 1] = (float)(fs / (double)NT);
        out[NT + TOTX + 2] = (float)sqrt(fmax(0.0, (sxx - sx * sx / sz) / sz));
    }
}

// --------------------------------------------------------------------- x_d ----
// Runs LAST: overwrites the scratch region with real x_d values.
__global__ __launch_bounds__(256) void xd_kernel(const float* __restrict__ mask,
                                                 const float* __restrict__ k,
                                                 float* __restrict__ out) {
    const int row = blockIdx.x * 256 + threadIdx.x;
    const int n = row >> 13, t = row & (T_DIM - 1);
    const int b = (int)out[row];
    const float m = mask[row];
    const float* kr = k + (size_t)b * C_DIM;
    float* xd = out + NT;
    #pragma unroll
    for (int c = 0; c < C_DIM; ++c)
        xd[((size_t)n * C_DIM + c) * T_DIM + t] = kr[c] * m;
}

// ----------------------------------------------------------------- launch ----
extern "C" void kernel_launch(void* const* d_in, const int* in_sizes, int n_in,
                              void* d_out, int out_size, void* d_ws, size_t ws_size,
                              hipStream_t stream) {
    (void)in_sizes; (void)n_in; (void)out_size; (void)d_ws; (void)ws_size;
    const float* x    = (const float*)d_in[0];
    const float* mask = (const float*)d_in[1];
    const float* k    = (const float*)d_in[2];
    float* out = (float*)d_out;

    kprep_kernel<<<KB / 256, 256, 0, stream>>>(k, out);
    argmin_kernel<<<NBLK, 256, 0, stream>>>(x, mask, out);
    fixup_kernel<<<1024, 256, 0, stream>>>(x, k, out);
    finalize_kernel<<<1, 256, 0, stream>>>(out);
    xd_kernel<<<NT / 256, 256, 0, stream>>>(mask, k, out);
}

// Round 16
// 135.246 us; speedup vs baseline: 23.4890x; 1.8777x over previous
//
#include <hip/hip_runtime.h>

#define T_DIM 8192
#define N_DIM 8
#define C_DIM 64
#define KB    2048
#define NT    (N_DIM * T_DIM)        // 65536 rows
#define TOTX  ((size_t)NT * C_DIM)   // 4194304 elements
#define NBLK  1024                   // argmin blocks (64 rows each)
#define LISTCAP 65536
#define TAU   0.04f

// Scratch inside out's x_d region (out + NT), overwritten LAST by xd_kernel.
// Offsets in FLOAT units from out+NT:
#define SCR_COUNT 0                   // int
#define SCR_LIST  16                  // int[65536]      -> ends 65552
#define SCR_PART  65792               // float[1024][8]  -> ends 73984
#define SCR_KNS   74240               // float[2048]     -> ends 76288
#define SCR_KK    76544               // float[2048]     -> ends 78592
#define SCR_K     81920               // f16x8 khi[16][8][128] (256 KB) -> 147456
#define SCR_FIX   262144              // float[65536][16] (4 MB) -> ends 1310720

typedef _Float16 half_t;
typedef _Float16 f16x8 __attribute__((ext_vector_type(8)));
typedef float    f32x16 __attribute__((ext_vector_type(16)));

// numpy pairwise sum (n=64) of squares (np-exact, fixup path).
__device__ __forceinline__ float np_sumsq64(const float* __restrict__ a) {
    float r[8];
    #pragma unroll
    for (int j = 0; j < 8; ++j) r[j] = __fmul_rn(a[j], a[j]);
    #pragma unroll
    for (int i = 8; i < 64; i += 8)
        #pragma unroll
        for (int j = 0; j < 8; ++j)
            r[j] = __fadd_rn(r[j], __fmul_rn(a[i + j], a[i + j]));
    return __fadd_rn(__fadd_rn(__fadd_rn(r[0], r[1]), __fadd_rn(r[2], r[3])),
                     __fadd_rn(__fadd_rn(r[4], r[5]), __fadd_rn(r[6], r[7])));
}

// ------------------------------------------------------------------ k prep ----
__global__ __launch_bounds__(256) void kprep_kernel(const float* __restrict__ k,
                                                    float* __restrict__ out) {
    float* base = out + NT;
    const int bin = blockIdx.x * 256 + threadIdx.x;   // grid 8 -> 2048
    if (bin == 0) ((int*)base)[SCR_COUNT] = 0;

    float kv[64];
    #pragma unroll
    for (int i = 0; i < 16; ++i)
        *(float4*)&kv[i * 4] = *(const float4*)(k + (size_t)bin * 64 + i * 4);

    float kn = 0.f;
    #pragma unroll
    for (int c = 0; c < 64; ++c) kn = fmaf(kv[c], kv[c], kn);
    base[SCR_KNS + bin] = kn;
    base[SCR_KK + bin]  = np_sumsq64(kv);

    f16x8* khi = (f16x8*)(base + SCR_K);
    const int ch = bin >> 7, b127 = bin & 127;
    #pragma unroll
    for (int slot = 0; slot < 8; ++slot) {
        f16x8 h8;
        #pragma unroll
        for (int e = 0; e < 8; ++e)
            h8[e] = (half_t)(-2.f * (float)((half_t)kv[slot * 8 + e]));
        khi[(size_t)ch * 1024 + slot * 128 + b127] = h8;
    }
}

// ------------------------------------------------------------------ argmin ----
__global__ __launch_bounds__(256, 2) void argmin_kernel(const float* __restrict__ x,
                                                        const float* __restrict__ mask,
                                                        float* __restrict__ out) {
    __shared__ __align__(16) f16x8 xhi_s[512];   // [8 slots][64 rows]
    __shared__ float kns_s[2048];
    __shared__ float psx[4][64], psxx[4][64];
    __shared__ float wres[2][64][3];

    float* base = out + NT;
    const int tid = threadIdx.x;
    const int l   = tid & 63, w = tid >> 6;
    const int col = l & 31, kg = l >> 5;
    const int rg  = w >> 1, hb = w & 1;
    const int r0  = blockIdx.x * 64;
    const int n   = r0 >> 13;
    const int t0  = r0 & (T_DIM - 1);

    #pragma unroll
    for (int i = 0; i < 8; ++i)
        kns_s[i * 256 + tid] = base[SCR_KNS + i * 256 + tid];

    {
        const int row = tid & 63, sp = tid >> 6;
        float sx = 0.f, sxx = 0.f;
        #pragma unroll
        for (int ss = 0; ss < 2; ++ss) {
            const int slot = sp * 2 + ss;
            f16x8 h8;
            #pragma unroll
            for (int e = 0; e < 8; ++e) {
                float v = x[((size_t)n * C_DIM + slot * 8 + e) * T_DIM + t0 + row];
                h8[e] = (half_t)v;
                sx += v; sxx = fmaf(v, v, sxx);
            }
            xhi_s[slot * 64 + row] = h8;
        }
        psx[sp][row]  = sx;
        psxx[sp][row] = sxx;
    }
    __syncthreads();

    f16x8 a0 = xhi_s[(0 + kg) * 64 + rg * 32 + col];
    f16x8 a1 = xhi_s[(2 + kg) * 64 + rg * 32 + col];
    f16x8 a2 = xhi_s[(4 + kg) * 64 + rg * 32 + col];
    f16x8 a3 = xhi_s[(6 + kg) * 64 + rg * 32 + col];

    const f16x8* kfw = (const f16x8*)(base + SCR_K)
                       + (size_t)hb * 8192 + kg * 128 + col;

    f32x16 zacc;
    #pragma unroll
    for (int r = 0; r < 16; ++r) zacc[r] = 0.f;

    float bestv[16], best2v[16];
    int   bestb[16];
    #pragma unroll
    for (int r = 0; r < 16; ++r) {
        bestv[r] = __builtin_inff(); best2v[r] = __builtin_inff(); bestb[r] = 0;
    }

    f16x8 bA[4], bB[4], bC[4], bD[4];

#define LOADT(t, BH)                                                \
    {                                                               \
        const f16x8* p = kfw + (((t) >> 2) * 1024 + ((t) & 3) * 32);\
        BH[0] = p[0]; BH[1] = p[256]; BH[2] = p[512]; BH[3] = p[768]; \
    }

#define COMPT(t, BH)                                                         \
    {                                                                        \
        const float kn = kns_s[hb * 1024 + (t) * 32 + col];                  \
        __builtin_amdgcn_s_setprio(1);                                       \
        f32x16 acc = __builtin_amdgcn_mfma_f32_32x32x16_f16(a0, BH[0], zacc, 0, 0, 0); \
        acc = __builtin_amdgcn_mfma_f32_32x32x16_f16(a1, BH[1], acc, 0, 0, 0); \
        acc = __builtin_amdgcn_mfma_f32_32x32x16_f16(a2, BH[2], acc, 0, 0, 0); \
        acc = __builtin_amdgcn_mfma_f32_32x32x16_f16(a3, BH[3], acc, 0, 0, 0); \
        __builtin_amdgcn_s_setprio(0);                                       \
        const int binf = hb * 1024 + (t) * 32 + col;                         \
        _Pragma("unroll")                                                    \
        for (int r = 0; r < 16; ++r) {                                       \
            float sv = acc[r] + kn;                                          \
            best2v[r] = fminf(best2v[r], fmaxf(sv, bestv[r]));               \
            if (sv < bestv[r]) { bestv[r] = sv; bestb[r] = binf; }           \
        }                                                                    \
    }

    LOADT(0, bA); LOADT(1, bB);
    #pragma unroll 1
    for (int t = 0; t < 24; t += 4) {
        LOADT(t + 2, bC); COMPT(t,     bA);
        LOADT(t + 3, bD); COMPT(t + 1, bB);
        LOADT(t + 4, bA); COMPT(t + 2, bC);
        LOADT(t + 5, bB); COMPT(t + 3, bD);
    }
    LOADT(26, bC); COMPT(24, bA);
    LOADT(27, bD); COMPT(25, bB);
    LOADT(28, bA); COMPT(26, bC);
    LOADT(29, bB); COMPT(27, bD);
    LOADT(30, bC); COMPT(28, bA);
    LOADT(31, bD); COMPT(29, bB);
    COMPT(30, bC);
    COMPT(31, bD);
#undef LOADT
#undef COMPT

    #pragma unroll
    for (int off = 1; off <= 16; off <<= 1) {
        #pragma unroll
        for (int r = 0; r < 16; ++r) {
            float ov = __shfl_xor(bestv[r], off, 64);
            int   ob = __shfl_xor(bestb[r], off, 64);
            float o2 = __shfl_xor(best2v[r], off, 64);
            float mx = fmaxf(bestv[r], ov);
            best2v[r] = fminf(fminf(best2v[r], o2), mx);
            if (ov < bestv[r] || (ov == bestv[r] && ob < bestb[r])) {
                bestv[r] = ov; bestb[r] = ob;
            }
        }
    }

    if (col == 0) {
        #pragma unroll
        for (int r = 0; r < 16; ++r) {
            const int row_loc = rg * 32 + 4 * kg + (r & 3) + 8 * (r >> 2);
            wres[hb][row_loc][0] = bestv[r];
            wres[hb][row_loc][1] = best2v[r];
            wres[hb][row_loc][2] = __int_as_float(bestb[r]);
        }
    }
    __syncthreads();

    if (tid < 64) {
        const int row = tid;
        const float v0 = wres[0][row][0], v1 = wres[1][row][0];
        float bv = v0; int bb = __float_as_int(wres[0][row][2]);
        if (v1 < bv) { bv = v1; bb = __float_as_int(wres[1][row][2]); }
        const float b2 = fminf(fminf(wres[0][row][1], wres[1][row][1]),
                               fmaxf(v0, v1));
        out[r0 + row] = (float)bb;
        if (b2 - bv < TAU) {
            int idx = atomicAdd((int*)base + SCR_COUNT, 1);
            if (idx < LISTCAP) ((int*)base + SCR_LIST)[idx] = r0 + row;
        }
        float sx = 0.f, sxx = 0.f;
        #pragma unroll
        for (int sp = 0; sp < 4; ++sp) { sx += psx[sp][row]; sxx += psxx[sp][row]; }
        const float m  = mask[r0 + row];
        const float d2 = sxx + bv;
        float vals[5] = { m * d2, d2, m, sx, sxx };
        #pragma unroll
        for (int off = 1; off <= 32; off <<= 1)
            #pragma unroll
            for (int q = 0; q < 5; ++q) vals[q] += __shfl_xor(vals[q], off, 64);
        if (tid == 0) {
            float* partials = base + SCR_PART;
            #pragma unroll
            for (int q = 0; q < 5; ++q)
                partials[(size_t)blockIdx.x * 8 + q] = vals[q];
        }
    }
}

// ------------------------------------------------------------------ fixup ----
// Work unit = (32-row batch) x (256-bin chunk). Each thread scans 32
// contiguous bins as 2 independent np-f32-exact chains; per-(row,chunk)
// partial (value,bin) -> SCR_FIX.
__global__ __launch_bounds__(256) void fixup_kernel(const float* __restrict__ x,
                                                    const float* __restrict__ k,
                                                    float* __restrict__ out) {
    __shared__ float xs[32][65];
    __shared__ float sxx_s[32];
    __shared__ float redv[256];
    __shared__ int   redb[256];

    const int tid = threadIdx.x;
    float* base = out + NT;
    const int* count    = (const int*)base + SCR_COUNT;
    const int* flaglist = (const int*)base + SCR_LIST;
    const float* kk     = base + SCR_KK;
    float* fix          = base + SCR_FIX;
    int cnt = *count;
    if (cnt > LISTCAP) cnt = LISTCAP;
    const int nb8 = ((cnt + 31) >> 5) << 3;

    const int rloc = tid & 31, part = tid >> 5;

    for (int wk = blockIdx.x; wk < nb8; wk += gridDim.x) {
        const int bi = wk >> 3, chunk = wk & 7;
        int li = bi * 32 + rloc;
        if (li >= cnt) li = bi * 32;                 // clamp (duplicate row ok)
        const int row = flaglist[li];
        const int n = row >> 13, t = row & (T_DIM - 1);
        #pragma unroll
        for (int e = 0; e < 8; ++e)
            xs[rloc][part * 8 + e] = x[((size_t)n * C_DIM + part * 8 + e) * T_DIM + t];
        __syncthreads();
        if (tid < 32) sxx_s[tid] = np_sumsq64(&xs[tid][0]);
        __syncthreads();

        float xr[64];
        #pragma unroll
        for (int c = 0; c < 64; ++c) xr[c] = xs[rloc][c];
        const float xx = sxx_s[rloc];

        float bv = __builtin_inff();
        int   bb = 0x7fffffff;
        const int bbase = chunk * 256 + part * 32;
        #pragma unroll 1
        for (int i = 0; i < 32; i += 2) {
            const int b0 = bbase + i;
            const int b1 = b0 + 1;
            const float* k0 = k + (size_t)b0 * 64;
            const float* k1 = k + (size_t)b1 * 64;
            float d0 = 0.f, d1 = 0.f;
            #pragma unroll
            for (int c = 0; c < 64; ++c) {
                d0 = fmaf(xr[c], k0[c], d0);
                d1 = fmaf(xr[c], k1[c], d1);
            }
            float s0 = __fadd_rn(__fsub_rn(xx, __fadd_rn(d0, d0)), kk[b0]);
            float s1 = __fadd_rn(__fsub_rn(xx, __fadd_rn(d1, d1)), kk[b1]);
            if (s0 < bv || (s0 == bv && b0 < bb)) { bv = s0; bb = b0; }
            if (s1 < bv || (s1 == bv && b1 < bb)) { bv = s1; bb = b1; }
        }
        redv[tid] = bv; redb[tid] = bb;
        __syncthreads();
        if (tid < 32) {
            float fv = redv[tid]; int fb = redb[tid];
            #pragma unroll
            for (int p = 1; p < 8; ++p) {
                float ov = redv[p * 32 + tid];
                int   ob = redb[p * 32 + tid];
                if (ov < fv || (ov == fv && ob < fb)) { fv = ov; fb = ob; }
            }
            const int fi = bi * 32 + tid;
            if (fi < cnt) {
                fix[(size_t)fi * 16 + chunk * 2]     = fv;
                fix[(size_t)fi * 16 + chunk * 2 + 1] = __int_as_float(fb);
            }
        }
        __syncthreads();
    }
}

// ---------------------------------------------------------------- fixmerge ----
__global__ __launch_bounds__(256) void fixmerge_kernel(float* __restrict__ out) {
    float* base = out + NT;
    const int* count    = (const int*)base + SCR_COUNT;
    const int* flaglist = (const int*)base + SCR_LIST;
    const float* fix    = base + SCR_FIX;
    int cnt = *count;
    if (cnt > LISTCAP) cnt = LISTCAP;

    for (int fi = blockIdx.x * 256 + threadIdx.x; fi < cnt;
         fi += gridDim.x * 256) {
        const float* p = fix + (size_t)fi * 16;
        float bv = p[0];
        int   bb = __float_as_int(p[1]);
        #pragma unroll
        for (int c = 1; c < 8; ++c) {
            float v = p[c * 2];
            int   b = __float_as_int(p[c * 2 + 1]);
            if (v < bv || (v == bv && b < bb)) { bv = v; bb = b; }
        }
        out[flaglist[fi]] = (float)bb;
    }
}

// ------------------------------------------------------------- finalize ----
__global__ __launch_bounds__(256) void finalize_kernel(float* __restrict__ out) {
    const float* partials = (out + NT) + SCR_PART;
    const int tid = threadIdx.x;
    double vals[5] = {0, 0, 0, 0, 0};
    for (int i = tid; i < NBLK; i += 256)
        #pragma unroll
        for (int q = 0; q < 5; ++q) vals[q] += (double)partials[(size_t)i * 8 + q];
    #pragma unroll
    for (int off = 1; off <= 32; off <<= 1)
        #pragma unroll
        for (int q = 0; q < 5; ++q) vals[q] += __shfl_xor(vals[q], off, 64);
    __shared__ double sred[4][5];
    const int wid = tid >> 6, lane = tid & 63;
    if (lane == 0)
        for (int q = 0; q < 5; ++q) sred[wid][q] = vals[q];
    __syncthreads();
    if (tid == 0) {
        double cm  = sred[0][0] + sred[1][0] + sred[2][0] + sred[3][0];
        double fs  = sred[0][1] + sred[1][1] + sred[2][1] + sred[3][1];
        double ms  = sred[0][2] + sred[1][2] + sred[2][2] + sred[3][2];
        double sx  = sred[0][3] + sred[1][3] + sred[2][3] + sred[3][3];
        double sxx = sred[0][4] + sred[1][4] + sred[2][4] + sred[3][4];
        double sz  = (double)TOTX;
        out[NT + TOTX + 0] = (float)(cm / (ms * (double)C_DIM));
        out[NT + TOTX + 1] = (float)(fs / (double)NT);
        out[NT + TOTX + 2] = (float)sqrt(fmax(0.0, (sxx - sx * sx / sz) / sz));
    }
}

// --------------------------------------------------------------------- x_d ----
__global__ __launch_bounds__(256) void xd_kernel(const float* __restrict__ mask,
                                                 const float* __restrict__ k,
                                                 float* __restrict__ out) {
    const int row = blockIdx.x * 256 + threadIdx.x;
    const int n = row >> 13, t = row & (T_DIM - 1);
    const int b = (int)out[row];
    const float m = mask[row];
    const float* kr = k + (size_t)b * C_DIM;
    float* xd = out + NT;
    #pragma unroll
    for (int c = 0; c < C_DIM; ++c)
        xd[((size_t)n * C_DIM + c) * T_DIM + t] = kr[c] * m;
}

// ----------------------------------------------------------------- launch ----
extern "C" void kernel_launch(void* const* d_in, const int* in_sizes, int n_in,
                              void* d_out, int out_size, void* d_ws, size_t ws_size,
                              hipStream_t stream) {
    (void)in_sizes; (void)n_in; (void)out_size; (void)d_ws; (void)ws_size;
    const float* x    = (const float*)d_in[0];
    const float* mask = (const float*)d_in[1];
    const float* k    = (const float*)d_in[2];
    float* out = (float*)d_out;

    kprep_kernel<<<KB / 256, 256, 0, stream>>>(k, out);
    argmin_kernel<<<NBLK, 256, 0, stream>>>(x, mask, out);
    fixup_kernel<<<2048, 256, 0, stream>>>(x, k, out);
    fixmerge_kernel<<<256, 256, 0, stream>>>(out);
    finalize_kernel<<<1, 256, 0, stream>>>(out);
    xd_kernel<<<NT / 256, 256, 0, stream>>>(mask, k, out);
}

// Round 17
// 106.175 us; speedup vs baseline: 29.9202x; 1.2738x over previous
//
#include <hip/hip_runtime.h>

#define T_DIM 8192
#define N_DIM 8
#define C_DIM 64
#define KB    2048
#define NT    (N_DIM * T_DIM)        // 65536 rows
#define TOTX  ((size_t)NT * C_DIM)   // 4194304 elements
#define NBLK  1024                   // argmin blocks (64 rows each)
#define LISTCAP 65536
#define TAU   0.04f

// Scratch inside out's x_d region (out + NT), overwritten LAST by xd_kernel.
// Offsets in FLOAT units from out+NT:
#define SCR_COUNT 0                   // int
#define SCR_LIST  16                  // int[65536]      -> ends 65552
#define SCR_PART  65792               // float[1024][8]  -> ends 73984
#define SCR_KNS   74240               // float[2048]     -> ends 76288
#define SCR_KK    76544               // float[2048]     -> ends 78592
#define SCR_K     81920               // f16x8 khi[16][8][128] (256 KB) -> 147456
#define SCR_FIX   262144              // float[65536][16] (4 MB) -> ends 1310720

typedef _Float16 half_t;
typedef _Float16 f16x8 __attribute__((ext_vector_type(8)));
typedef float    f32x16 __attribute__((ext_vector_type(16)));

// numpy pairwise sum (n=64) of squares (np-exact, fixup path).
__device__ __forceinline__ float np_sumsq64(const float* __restrict__ a) {
    float r[8];
    #pragma unroll
    for (int j = 0; j < 8; ++j) r[j] = __fmul_rn(a[j], a[j]);
    #pragma unroll
    for (int i = 8; i < 64; i += 8)
        #pragma unroll
        for (int j = 0; j < 8; ++j)
            r[j] = __fadd_rn(r[j], __fmul_rn(a[i + j], a[i + j]));
    return __fadd_rn(__fadd_rn(__fadd_rn(r[0], r[1]), __fadd_rn(r[2], r[3])),
                     __fadd_rn(__fadd_rn(r[4], r[5]), __fadd_rn(r[6], r[7])));
}

// ------------------------------------------------------------------ k prep ----
__global__ __launch_bounds__(256) void kprep_kernel(const float* __restrict__ k,
                                                    float* __restrict__ out) {
    float* base = out + NT;
    const int bin = blockIdx.x * 256 + threadIdx.x;   // grid 8 -> 2048
    if (bin == 0) ((int*)base)[SCR_COUNT] = 0;

    float kv[64];
    #pragma unroll
    for (int i = 0; i < 16; ++i)
        *(float4*)&kv[i * 4] = *(const float4*)(k + (size_t)bin * 64 + i * 4);

    float kn = 0.f;
    #pragma unroll
    for (int c = 0; c < 64; ++c) kn = fmaf(kv[c], kv[c], kn);
    base[SCR_KNS + bin] = kn;
    base[SCR_KK + bin]  = np_sumsq64(kv);

    f16x8* khi = (f16x8*)(base + SCR_K);
    const int ch = bin >> 7, b127 = bin & 127;
    #pragma unroll
    for (int slot = 0; slot < 8; ++slot) {
        f16x8 h8;
        #pragma unroll
        for (int e = 0; e < 8; ++e)
            h8[e] = (half_t)(-2.f * (float)((half_t)kv[slot * 8 + e]));
        khi[(size_t)ch * 1024 + slot * 128 + b127] = h8;
    }
}

// ------------------------------------------------------------------ argmin ----
// Grid 1024, block = 64 rows x 4 waves: wave w -> (rg=w>>1 rows, hb=w&1 bins).
// hi-only filter (4 MFMA/tile). TWO rotating reg buffers (distance-1
// prefetch), no setprio, acc init from kn — R10-proven non-spilling shape.
__global__ __launch_bounds__(256, 2) void argmin_kernel(const float* __restrict__ x,
                                                        const float* __restrict__ mask,
                                                        float* __restrict__ out) {
    __shared__ __align__(16) f16x8 xhi_s[512];   // [8 slots][64 rows]
    __shared__ float kns_s[2048];
    __shared__ float psx[4][64], psxx[4][64];
    __shared__ float wres[2][64][3];

    float* base = out + NT;
    const int tid = threadIdx.x;
    const int l   = tid & 63, w = tid >> 6;
    const int col = l & 31, kg = l >> 5;
    const int rg  = w >> 1, hb = w & 1;
    const int r0  = blockIdx.x * 64;
    const int n   = r0 >> 13;
    const int t0  = r0 & (T_DIM - 1);

    #pragma unroll
    for (int i = 0; i < 8; ++i)
        kns_s[i * 256 + tid] = base[SCR_KNS + i * 256 + tid];

    // prologue: x load + f16-hi split + row stats (thread: row=tid&63, 2 slots)
    {
        const int row = tid & 63, sp = tid >> 6;
        float sx = 0.f, sxx = 0.f;
        #pragma unroll
        for (int ss = 0; ss < 2; ++ss) {
            const int slot = sp * 2 + ss;
            f16x8 h8;
            #pragma unroll
            for (int e = 0; e < 8; ++e) {
                float v = x[((size_t)n * C_DIM + slot * 8 + e) * T_DIM + t0 + row];
                h8[e] = (half_t)v;
                sx += v; sxx = fmaf(v, v, sxx);
            }
            xhi_s[slot * 64 + row] = h8;
        }
        psx[sp][row]  = sx;
        psxx[sp][row] = sxx;
    }
    __syncthreads();

    // A fragments: rows rg*32 + col, K=64 over 4 k-steps
    f16x8 a0 = xhi_s[(0 + kg) * 64 + rg * 32 + col];
    f16x8 a1 = xhi_s[(2 + kg) * 64 + rg * 32 + col];
    f16x8 a2 = xhi_s[(4 + kg) * 64 + rg * 32 + col];
    f16x8 a3 = xhi_s[(6 + kg) * 64 + rg * 32 + col];

    // per-wave k base (bin half hb)
    const f16x8* kfw = (const f16x8*)(base + SCR_K)
                       + (size_t)hb * 8192 + kg * 128 + col;

    float bestv[16], best2v[16];
    int   bestb[16];
    #pragma unroll
    for (int r = 0; r < 16; ++r) {
        bestv[r] = __builtin_inff(); best2v[r] = __builtin_inff(); bestb[r] = 0;
    }

    f16x8 bA[4], bB[4];

#define LOADT(t, BH)                                                \
    {                                                               \
        const f16x8* p = kfw + (((t) >> 2) * 1024 + ((t) & 3) * 32);\
        BH[0] = p[0]; BH[1] = p[256]; BH[2] = p[512]; BH[3] = p[768]; \
    }

#define COMPT(t, BH)                                                         \
    {                                                                        \
        const float kn = kns_s[hb * 1024 + (t) * 32 + col];                  \
        f32x16 acc;                                                          \
        _Pragma("unroll")                                                    \
        for (int r = 0; r < 16; ++r) acc[r] = kn;                            \
        acc = __builtin_amdgcn_mfma_f32_32x32x16_f16(a0, BH[0], acc, 0, 0, 0); \
        acc = __builtin_amdgcn_mfma_f32_32x32x16_f16(a1, BH[1], acc, 0, 0, 0); \
        acc = __builtin_amdgcn_mfma_f32_32x32x16_f16(a2, BH[2], acc, 0, 0, 0); \
        acc = __builtin_amdgcn_mfma_f32_32x32x16_f16(a3, BH[3], acc, 0, 0, 0); \
        const int binf = hb * 1024 + (t) * 32 + col;                         \
        _Pragma("unroll")                                                    \
        for (int r = 0; r < 16; ++r) {                                       \
            float sv = acc[r];                                               \
            best2v[r] = fminf(best2v[r], fmaxf(sv, bestv[r]));               \
            if (sv < bestv[r]) { bestv[r] = sv; bestb[r] = binf; }           \
        }                                                                    \
    }

    LOADT(0, bA);
    #pragma unroll 1
    for (int t = 0; t < 30; t += 2) {
        LOADT(t + 1, bB);
        COMPT(t, bA);
        LOADT(t + 2, bA);
        COMPT(t + 1, bB);
    }
    LOADT(31, bB);
    COMPT(30, bA);
    COMPT(31, bB);
#undef LOADT
#undef COMPT

    // merge across the 32 column-lanes of each half, tracking 2nd-best
    #pragma unroll
    for (int off = 1; off <= 16; off <<= 1) {
        #pragma unroll
        for (int r = 0; r < 16; ++r) {
            float ov = __shfl_xor(bestv[r], off, 64);
            int   ob = __shfl_xor(bestb[r], off, 64);
            float o2 = __shfl_xor(best2v[r], off, 64);
            float mx = fmaxf(bestv[r], ov);
            best2v[r] = fminf(fminf(best2v[r], o2), mx);
            if (ov < bestv[r] || (ov == bestv[r] && ob < bestb[r])) {
                bestv[r] = ov; bestb[r] = ob;
            }
        }
    }

    // stash per-(bin-half, row) results
    if (col == 0) {
        #pragma unroll
        for (int r = 0; r < 16; ++r) {
            const int row_loc = rg * 32 + 4 * kg + (r & 3) + 8 * (r >> 2);
            wres[hb][row_loc][0] = bestv[r];
            wres[hb][row_loc][1] = best2v[r];
            wres[hb][row_loc][2] = __int_as_float(bestb[r]);
        }
    }
    __syncthreads();

    // final merge: threads 0..63 (wave 0) own one row each
    if (tid < 64) {
        const int row = tid;
        const float v0 = wres[0][row][0], v1 = wres[1][row][0];
        float bv = v0; int bb = __float_as_int(wres[0][row][2]);
        if (v1 < bv) { bv = v1; bb = __float_as_int(wres[1][row][2]); }
        const float b2 = fminf(fminf(wres[0][row][1], wres[1][row][1]),
                               fmaxf(v0, v1));
        out[r0 + row] = (float)bb;
        if (b2 - bv < TAU) {
            int idx = atomicAdd((int*)base + SCR_COUNT, 1);
            if (idx < LISTCAP) ((int*)base + SCR_LIST)[idx] = r0 + row;
        }
        float sx = 0.f, sxx = 0.f;
        #pragma unroll
        for (int sp = 0; sp < 4; ++sp) { sx += psx[sp][row]; sxx += psxx[sp][row]; }
        const float m  = mask[r0 + row];
        const float d2 = sxx + bv;
        float vals[5] = { m * d2, d2, m, sx, sxx };
        #pragma unroll
        for (int off = 1; off <= 32; off <<= 1)
            #pragma unroll
            for (int q = 0; q < 5; ++q) vals[q] += __shfl_xor(vals[q], off, 64);
        if (tid == 0) {
            float* partials = base + SCR_PART;
            #pragma unroll
            for (int q = 0; q < 5; ++q)
                partials[(size_t)blockIdx.x * 8 + q] = vals[q];
        }
    }
}

// ------------------------------------------------------------------ fixup ----
// Work unit = (32-row batch) x (256-bin chunk). Each thread scans 32
// contiguous bins as 2 independent np-f32-exact chains; per-(row,chunk)
// partial (value,bin) -> SCR_FIX.
__global__ __launch_bounds__(256) void fixup_kernel(const float* __restrict__ x,
                                                    const float* __restrict__ k,
                                                    float* __restrict__ out) {
    __shared__ float xs[32][65];
    __shared__ float sxx_s[32];
    __shared__ float redv[256];
    __shared__ int   redb[256];

    const int tid = threadIdx.x;
    float* base = out + NT;
    const int* count    = (const int*)base + SCR_COUNT;
    const int* flaglist = (const int*)base + SCR_LIST;
    const float* kk     = base + SCR_KK;
    float* fix          = base + SCR_FIX;
    int cnt = *count;
    if (cnt > LISTCAP) cnt = LISTCAP;
    const int nb8 = ((cnt + 31) >> 5) << 3;

    const int rloc = tid & 31, part = tid >> 5;

    for (int wk = blockIdx.x; wk < nb8; wk += gridDim.x) {
        const int bi = wk >> 3, chunk = wk & 7;
        int li = bi * 32 + rloc;
        if (li >= cnt) li = bi * 32;                 // clamp (duplicate row ok)
        const int row = flaglist[li];
        const int n = row >> 13, t = row & (T_DIM - 1);
        #pragma unroll
        for (int e = 0; e < 8; ++e)
            xs[rloc][part * 8 + e] = x[((size_t)n * C_DIM + part * 8 + e) * T_DIM + t];
        __syncthreads();
        if (tid < 32) sxx_s[tid] = np_sumsq64(&xs[tid][0]);
        __syncthreads();

        float xr[64];
        #pragma unroll
        for (int c = 0; c < 64; ++c) xr[c] = xs[rloc][c];
        const float xx = sxx_s[rloc];

        float bv = __builtin_inff();
        int   bb = 0x7fffffff;
        const int bbase = chunk * 256 + part * 32;
        #pragma unroll 1
        for (int i = 0; i < 32; i += 2) {
            const int b0 = bbase + i;
            const int b1 = b0 + 1;
            const float* k0 = k + (size_t)b0 * 64;
            const float* k1 = k + (size_t)b1 * 64;
            float d0 = 0.f, d1 = 0.f;
            #pragma unroll
            for (int c = 0; c < 64; ++c) {
                d0 = fmaf(xr[c], k0[c], d0);
                d1 = fmaf(xr[c], k1[c], d1);
            }
            float s0 = __fadd_rn(__fsub_rn(xx, __fadd_rn(d0, d0)), kk[b0]);
            float s1 = __fadd_rn(__fsub_rn(xx, __fadd_rn(d1, d1)), kk[b1]);
            if (s0 < bv || (s0 == bv && b0 < bb)) { bv = s0; bb = b0; }
            if (s1 < bv || (s1 == bv && b1 < bb)) { bv = s1; bb = b1; }
        }
        redv[tid] = bv; redb[tid] = bb;
        __syncthreads();
        if (tid < 32) {
            float fv = redv[tid]; int fb = redb[tid];
            #pragma unroll
            for (int p = 1; p < 8; ++p) {
                float ov = redv[p * 32 + tid];
                int   ob = redb[p * 32 + tid];
                if (ov < fv || (ov == fv && ob < fb)) { fv = ov; fb = ob; }
            }
            const int fi = bi * 32 + tid;
            if (fi < cnt) {
                fix[(size_t)fi * 16 + chunk * 2]     = fv;
                fix[(size_t)fi * 16 + chunk * 2 + 1] = __int_as_float(fb);
            }
        }
        __syncthreads();
    }
}

// ---------------------------------------------------------------- fixmerge ----
__global__ __launch_bounds__(256) void fixmerge_kernel(float* __restrict__ out) {
    float* base = out + NT;
    const int* count    = (const int*)base + SCR_COUNT;
    const int* flaglist = (const int*)base + SCR_LIST;
    const float* fix    = base + SCR_FIX;
    int cnt = *count;
    if (cnt > LISTCAP) cnt = LISTCAP;

    for (int fi = blockIdx.x * 256 + threadIdx.x; fi < cnt;
         fi += gridDim.x * 256) {
        const float* p = fix + (size_t)fi * 16;
        float bv = p[0];
        int   bb = __float_as_int(p[1]);
        #pragma unroll
        for (int c = 1; c < 8; ++c) {
            float v = p[c * 2];
            int   b = __float_as_int(p[c * 2 + 1]);
            if (v < bv || (v == bv && b < bb)) { bv = v; bb = b; }
        }
        out[flaglist[fi]] = (float)bb;
    }
}

// ------------------------------------------------------------- finalize ----
__global__ __launch_bounds__(256) void finalize_kernel(float* __restrict__ out) {
    const float* partials = (out + NT) + SCR_PART;
    const int tid = threadIdx.x;
    double vals[5] = {0, 0, 0, 0, 0};
    for (int i = tid; i < NBLK; i += 256)
        #pragma unroll
        for (int q = 0; q < 5; ++q) vals[q] += (double)partials[(size_t)i * 8 + q];
    #pragma unroll
    for (int off = 1; off <= 32; off <<= 1)
        #pragma unroll
        for (int q = 0; q < 5; ++q) vals[q] += __shfl_xor(vals[q], off, 64);
    __shared__ double sred[4][5];
    const int wid = tid >> 6, lane = tid & 63;
    if (lane == 0)
        for (int q = 0; q < 5; ++q) sred[wid][q] = vals[q];
    __syncthreads();
    if (tid == 0) {
        double cm  = sred[0][0] + sred[1][0] + sred[2][0] + sred[3][0];
        double fs  = sred[0][1] + sred[1][1] + sred[2][1] + sred[3][1];
        double ms  = sred[0][2] + sred[1][2] + sred[2][2] + sred[3][2];
        double sx  = sred[0][3] + sred[1][3] + sred[2][3] + sred[3][3];
        double sxx = sred[0][4] + sred[1][4] + sred[2][4] + sred[3][4];
        double sz  = (double)TOTX;
        out[NT + TOTX + 0] = (float)(cm / (ms * (double)C_DIM));
        out[NT + TOTX + 1] = (float)(fs / (double)NT);
        out[NT + TOTX + 2] = (float)sqrt(fmax(0.0, (sxx - sx * sx / sz) / sz));
    }
}

// --------------------------------------------------------------------- x_d ----
__global__ __launch_bounds__(256) void xd_kernel(const float* __restrict__ mask,
                                                 const float* __restrict__ k,
                                                 float* __restrict__ out) {
    const int row = blockIdx.x * 256 + threadIdx.x;
    const int n = row >> 13, t = row & (T_DIM - 1);
    const int b = (int)out[row];
    const float m = mask[row];
    const float* kr = k + (size_t)b * C_DIM;
    float* xd = out + NT;
    #pragma unroll
    for (int c = 0; c < C_DIM; ++c)
        xd[((size_t)n * C_DIM + c) * T_DIM + t] = kr[c] * m;
}

// ----------------------------------------------------------------- launch ----
extern "C" void kernel_launch(void* const* d_in, const int* in_sizes, int n_in,
                              void* d_out, int out_size, void* d_ws, size_t ws_size,
                              hipStream_t stream) {
    (void)in_sizes; (void)n_in; (void)out_size; (void)d_ws; (void)ws_size;
    const float* x    = (const float*)d_in[0];
    const float* mask = (const float*)d_in[1];
    const float* k    = (const float*)d_in[2];
    float* out = (float*)d_out;

    kprep_kernel<<<KB / 256, 256, 0, stream>>>(k, out);
    argmin_kernel<<<NBLK, 256, 0, stream>>>(x, mask, out);
    fixup_kernel<<<2048, 256, 0, stream>>>(x, k, out);
    fixmerge_kernel<<<256, 256, 0, stream>>>(out);
    finalize_kernel<<<1, 256, 0, stream>>>(out);
    xd_kernel<<<NT / 256, 256, 0, stream>>>(mask, k, out);
}

// Round 18
// 103.018 us; speedup vs baseline: 30.8371x; 1.0306x over previous
//
#include <hip/hip_runtime.h>

#define T_DIM 8192
#define N_DIM 8
#define C_DIM 64
#define KB    2048
#define NT    (N_DIM * T_DIM)        // 65536 rows
#define TOTX  ((size_t)NT * C_DIM)   // 4194304 elements
#define NBLK  1024                   // argmin blocks (64 rows each)
#define LISTCAP 65536
#define TAU   0.04f

// Scratch inside out's x_d region (out + NT), overwritten LAST by xd_kernel.
// Offsets in FLOAT units from out+NT:
#define SCR_COUNT 0                   // int
#define SCR_LIST  16                  // int[65536]      -> ends 65552
#define SCR_PART  65792               // float[1024][8]  -> ends 73984
#define SCR_KK    76544               // float[2048]     -> ends 78592
#define SCR_K     81920               // f16x8 k9[16][9][128] (288 KB) -> 155648
#define SCR_FIX   262144              // float[65536][16] (4 MB) -> ends 1310720

typedef _Float16 half_t;
typedef _Float16 f16x8 __attribute__((ext_vector_type(8)));
typedef float    f32x16 __attribute__((ext_vector_type(16)));

// numpy pairwise sum (n=64) of squares (np-exact, fixup path).
__device__ __forceinline__ float np_sumsq64(const float* __restrict__ a) {
    float r[8];
    #pragma unroll
    for (int j = 0; j < 8; ++j) r[j] = __fmul_rn(a[j], a[j]);
    #pragma unroll
    for (int i = 8; i < 64; i += 8)
        #pragma unroll
        for (int j = 0; j < 8; ++j)
            r[j] = __fadd_rn(r[j], __fmul_rn(a[i + j], a[i + j]));
    return __fadd_rn(__fadd_rn(__fadd_rn(r[0], r[1]), __fadd_rn(r[2], r[3])),
                     __fadd_rn(__fadd_rn(r[4], r[5]), __fadd_rn(r[6], r[7])));
}

// ------------------------------------------------------------------ k prep ----
// 9-slot layout per 128-bin chunk: slots 0..7 = -2*f16(k) [slot][bin];
// slot 8 = (kn_hi, kn_lo, 0...) f16 pair of seq-fma ||k||^2 (injected via a
// 5th MFMA K-step). kk = np-exact ||k||^2 (fixup).
__global__ __launch_bounds__(256) void kprep_kernel(const float* __restrict__ k,
                                                    float* __restrict__ out) {
    float* base = out + NT;
    const int bin = blockIdx.x * 256 + threadIdx.x;   // grid 8 -> 2048
    if (bin == 0) ((int*)base)[SCR_COUNT] = 0;

    float kv[64];
    #pragma unroll
    for (int i = 0; i < 16; ++i)
        *(float4*)&kv[i * 4] = *(const float4*)(k + (size_t)bin * 64 + i * 4);

    float kn = 0.f;
    #pragma unroll
    for (int c = 0; c < 64; ++c) kn = fmaf(kv[c], kv[c], kn);
    base[SCR_KK + bin] = np_sumsq64(kv);

    f16x8* kscr = (f16x8*)(base + SCR_K);
    const int ch = bin >> 7, b127 = bin & 127;
    #pragma unroll
    for (int slot = 0; slot < 8; ++slot) {
        f16x8 h8;
        #pragma unroll
        for (int e = 0; e < 8; ++e)
            h8[e] = (half_t)(-2.f * (float)((half_t)kv[slot * 8 + e]));
        kscr[(size_t)ch * 1152 + slot * 128 + b127] = h8;
    }
    {
        half_t knh = (half_t)kn;
        half_t knl = (half_t)(kn - (float)knh);
        f16x8 k8;
        #pragma unroll
        for (int e = 0; e < 8; ++e) k8[e] = (half_t)0.f;
        k8[0] = knh; k8[1] = knl;
        kscr[(size_t)ch * 1152 + 1024 + b127] = k8;
    }
}

// ------------------------------------------------------------------ argmin ----
// Grid 1024, block = 64 rows x 4 waves: wave w -> (rg=w>>1 rows, hb=w&1 bins).
// hi-only filter, 5 MFMA/tile (4 products + kn-inject), med3 second-best,
// two rotating reg buffers, no k-loop barriers.
__global__ __launch_bounds__(256, 2) void argmin_kernel(const float* __restrict__ x,
                                                        const float* __restrict__ mask,
                                                        float* __restrict__ out) {
    __shared__ __align__(16) f16x8 xhi_s[512];   // [8 slots][64 rows]
    __shared__ float psx[4][64], psxx[4][64];
    __shared__ float wres[2][64][3];

    float* base = out + NT;
    const int tid = threadIdx.x;
    const int l   = tid & 63, w = tid >> 6;
    const int col = l & 31, kg = l >> 5;
    const int rg  = w >> 1, hb = w & 1;
    const int r0  = blockIdx.x * 64;
    const int n   = r0 >> 13;
    const int t0  = r0 & (T_DIM - 1);

    // prologue: x load + f16-hi split + row stats (thread: row=tid&63, 2 slots)
    {
        const int row = tid & 63, sp = tid >> 6;
        float sx = 0.f, sxx = 0.f;
        #pragma unroll
        for (int ss = 0; ss < 2; ++ss) {
            const int slot = sp * 2 + ss;
            f16x8 h8;
            #pragma unroll
            for (int e = 0; e < 8; ++e) {
                float v = x[((size_t)n * C_DIM + slot * 8 + e) * T_DIM + t0 + row];
                h8[e] = (half_t)v;
                sx += v; sxx = fmaf(v, v, sxx);
            }
            xhi_s[slot * 64 + row] = h8;
        }
        psx[sp][row]  = sx;
        psxx[sp][row] = sxx;
    }
    __syncthreads();

    // A fragments: rows rg*32 + col, K=64 over 4 k-steps + kn-inject frag
    f16x8 a0 = xhi_s[(0 + kg) * 64 + rg * 32 + col];
    f16x8 a1 = xhi_s[(2 + kg) * 64 + rg * 32 + col];
    f16x8 a2 = xhi_s[(4 + kg) * 64 + rg * 32 + col];
    f16x8 a3 = xhi_s[(6 + kg) * 64 + rg * 32 + col];
    f16x8 a4;
    #pragma unroll
    for (int e = 0; e < 8; ++e) a4[e] = (half_t)0.f;
    if (kg == 0) { a4[0] = (half_t)1.f; a4[1] = (half_t)1.f; }

    // per-wave k base (bin half hb); chunk stride 1152 f16x8 (9 slots x 128)
    const f16x8* kf0 = (const f16x8*)(base + SCR_K) + (size_t)hb * 9216 + col;
    const int kgo = kg * 128;

    f32x16 zacc;
    #pragma unroll
    for (int r = 0; r < 16; ++r) zacc[r] = 0.f;

    float bestv[16], best2v[16];
    int   bestb[16];
    #pragma unroll
    for (int r = 0; r < 16; ++r) {
        bestv[r] = __builtin_inff(); best2v[r] = __builtin_inff(); bestb[r] = 0;
    }

    f16x8 bA[4], bB[4], b4A, b4B;

#define LOADT(t, BH, B4)                                            \
    {                                                               \
        const f16x8* p = kf0 + (((t) >> 2) * 1152 + ((t) & 3) * 32);\
        BH[0] = p[kgo]; BH[1] = p[kgo + 256];                       \
        BH[2] = p[kgo + 512]; BH[3] = p[kgo + 768];                 \
        B4 = p[1024];                                               \
    }

#define COMPT(t, BH, B4)                                                     \
    {                                                                        \
        f32x16 acc = __builtin_amdgcn_mfma_f32_32x32x16_f16(a4, B4, zacc, 0, 0, 0); \
        acc = __builtin_amdgcn_mfma_f32_32x32x16_f16(a0, BH[0], acc, 0, 0, 0); \
        acc = __builtin_amdgcn_mfma_f32_32x32x16_f16(a1, BH[1], acc, 0, 0, 0); \
        acc = __builtin_amdgcn_mfma_f32_32x32x16_f16(a2, BH[2], acc, 0, 0, 0); \
        acc = __builtin_amdgcn_mfma_f32_32x32x16_f16(a3, BH[3], acc, 0, 0, 0); \
        const int binf = hb * 1024 + (t) * 32 + col;                         \
        _Pragma("unroll")                                                    \
        for (int r = 0; r < 16; ++r) {                                       \
            float sv = acc[r];                                               \
            float nb2;                                                       \
            asm("v_med3_f32 %0, %1, %2, %3"                                  \
                : "=v"(nb2) : "v"(sv), "v"(bestv[r]), "v"(best2v[r]));       \
            best2v[r] = nb2;                                                 \
            if (sv < bestv[r]) { bestv[r] = sv; bestb[r] = binf; }           \
        }                                                                    \
    }

    LOADT(0, bA, b4A);
    #pragma unroll 1
    for (int t = 0; t < 30; t += 2) {
        LOADT(t + 1, bB, b4B);
        COMPT(t, bA, b4A);
        LOADT(t + 2, bA, b4A);
        COMPT(t + 1, bB, b4B);
    }
    LOADT(31, bB, b4B);
    COMPT(30, bA, b4A);
    COMPT(31, bB, b4B);
#undef LOADT
#undef COMPT

    // merge across the 32 column-lanes of each half, tracking 2nd-best
    #pragma unroll
    for (int off = 1; off <= 16; off <<= 1) {
        #pragma unroll
        for (int r = 0; r < 16; ++r) {
            float ov = __shfl_xor(bestv[r], off, 64);
            int   ob = __shfl_xor(bestb[r], off, 64);
            float o2 = __shfl_xor(best2v[r], off, 64);
            float mx = fmaxf(bestv[r], ov);
            best2v[r] = fminf(fminf(best2v[r], o2), mx);
            if (ov < bestv[r] || (ov == bestv[r] && ob < bestb[r])) {
                bestv[r] = ov; bestb[r] = ob;
            }
        }
    }

    // stash per-(bin-half, row) results
    if (col == 0) {
        #pragma unroll
        for (int r = 0; r < 16; ++r) {
            const int row_loc = rg * 32 + 4 * kg + (r & 3) + 8 * (r >> 2);
            wres[hb][row_loc][0] = bestv[r];
            wres[hb][row_loc][1] = best2v[r];
            wres[hb][row_loc][2] = __int_as_float(bestb[r]);
        }
    }
    __syncthreads();

    // final merge: threads 0..63 (wave 0) own one row each
    if (tid < 64) {
        const int row = tid;
        const float v0 = wres[0][row][0], v1 = wres[1][row][0];
        float bv = v0; int bb = __float_as_int(wres[0][row][2]);
        if (v1 < bv) { bv = v1; bb = __float_as_int(wres[1][row][2]); }
        const float b2 = fminf(fminf(wres[0][row][1], wres[1][row][1]),
                               fmaxf(v0, v1));
        out[r0 + row] = (float)bb;
        if (b2 - bv < TAU) {
            int idx = atomicAdd((int*)base + SCR_COUNT, 1);
            if (idx < LISTCAP) ((int*)base + SCR_LIST)[idx] = r0 + row;
        }
        float sx = 0.f, sxx = 0.f;
        #pragma unroll
        for (int sp = 0; sp < 4; ++sp) { sx += psx[sp][row]; sxx += psxx[sp][row]; }
        const float m  = mask[r0 + row];
        const float d2 = sxx + bv;
        float vals[5] = { m * d2, d2, m, sx, sxx };
        #pragma unroll
        for (int off = 1; off <= 32; off <<= 1)
            #pragma unroll
            for (int q = 0; q < 5; ++q) vals[q] += __shfl_xor(vals[q], off, 64);
        if (tid == 0) {
            float* partials = base + SCR_PART;
            #pragma unroll
            for (int q = 0; q < 5; ++q)
                partials[(size_t)blockIdx.x * 8 + q] = vals[q];
        }
    }
}

// ------------------------------------------------------------------ fixup ----
// Work unit = (32-row batch) x (256-bin chunk). Each thread scans 32
// contiguous bins as 2 independent np-f32-exact chains; per-(row,chunk)
// partial (value,bin) -> SCR_FIX.
__global__ __launch_bounds__(256) void fixup_kernel(const float* __restrict__ x,
                                                    const float* __restrict__ k,
                                                    float* __restrict__ out) {
    __shared__ float xs[32][65];
    __shared__ float sxx_s[32];
    __shared__ float redv[256];
    __shared__ int   redb[256];

    const int tid = threadIdx.x;
    float* base = out + NT;
    const int* count    = (const int*)base + SCR_COUNT;
    const int* flaglist = (const int*)base + SCR_LIST;
    const float* kk     = base + SCR_KK;
    float* fix          = base + SCR_FIX;
    int cnt = *count;
    if (cnt > LISTCAP) cnt = LISTCAP;
    const int nb8 = ((cnt + 31) >> 5) << 3;

    const int rloc = tid & 31, part = tid >> 5;

    for (int wk = blockIdx.x; wk < nb8; wk += gridDim.x) {
        const int bi = wk >> 3, chunk = wk & 7;
        int li = bi * 32 + rloc;
        if (li >= cnt) li = bi * 32;                 // clamp (duplicate row ok)
        const int row = flaglist[li];
        const int n = row >> 13, t = row & (T_DIM - 1);
        #pragma unroll
        for (int e = 0; e < 8; ++e)
            xs[rloc][part * 8 + e] = x[((size_t)n * C_DIM + part * 8 + e) * T_DIM + t];
        __syncthreads();
        if (tid < 32) sxx_s[tid] = np_sumsq64(&xs[tid][0]);
        __syncthreads();

        float xr[64];
        #pragma unroll
        for (int c = 0; c < 64; ++c) xr[c] = xs[rloc][c];
        const float xx = sxx_s[rloc];

        float bv = __builtin_inff();
        int   bb = 0x7fffffff;
        const int bbase = chunk * 256 + part * 32;
        #pragma unroll 1
        for (int i = 0; i < 32; i += 2) {
            const int b0 = bbase + i;
            const int b1 = b0 + 1;
            const float* k0 = k + (size_t)b0 * 64;
            const float* k1 = k + (size_t)b1 * 64;
            float d0 = 0.f, d1 = 0.f;
            #pragma unroll
            for (int c = 0; c < 64; ++c) {
                d0 = fmaf(xr[c], k0[c], d0);
                d1 = fmaf(xr[c], k1[c], d1);
            }
            float s0 = __fadd_rn(__fsub_rn(xx, __fadd_rn(d0, d0)), kk[b0]);
            float s1 = __fadd_rn(__fsub_rn(xx, __fadd_rn(d1, d1)), kk[b1]);
            if (s0 < bv || (s0 == bv && b0 < bb)) { bv = s0; bb = b0; }
            if (s1 < bv || (s1 == bv && b1 < bb)) { bv = s1; bb = b1; }
        }
        redv[tid] = bv; redb[tid] = bb;
        __syncthreads();
        if (tid < 32) {
            float fv = redv[tid]; int fb = redb[tid];
            #pragma unroll
            for (int p = 1; p < 8; ++p) {
                float ov = redv[p * 32 + tid];
                int   ob = redb[p * 32 + tid];
                if (ov < fv || (ov == fv && ob < fb)) { fv = ov; fb = ob; }
            }
            const int fi = bi * 32 + tid;
            if (fi < cnt) {
                fix[(size_t)fi * 16 + chunk * 2]     = fv;
                fix[(size_t)fi * 16 + chunk * 2 + 1] = __int_as_float(fb);
            }
        }
        __syncthreads();
    }
}

// ---------------------------------------------------------------- fixmerge ----
__global__ __launch_bounds__(256) void fixmerge_kernel(float* __restrict__ out) {
    float* base = out + NT;
    const int* count    = (const int*)base + SCR_COUNT;
    const int* flaglist = (const int*)base + SCR_LIST;
    const float* fix    = base + SCR_FIX;
    int cnt = *count;
    if (cnt > LISTCAP) cnt = LISTCAP;

    for (int fi = blockIdx.x * 256 + threadIdx.x; fi < cnt;
         fi += gridDim.x * 256) {
        const float* p = fix + (size_t)fi * 16;
        float bv = p[0];
        int   bb = __float_as_int(p[1]);
        #pragma unroll
        for (int c = 1; c < 8; ++c) {
            float v = p[c * 2];
            int   b = __float_as_int(p[c * 2 + 1]);
            if (v < bv || (v == bv && b < bb)) { bv = v; bb = b; }
        }
        out[flaglist[fi]] = (float)bb;
    }
}

// ------------------------------------------------------------- finalize ----
__global__ __launch_bounds__(256) void finalize_kernel(float* __restrict__ out) {
    const float* partials = (out + NT) + SCR_PART;
    const int tid = threadIdx.x;
    double vals[5] = {0, 0, 0, 0, 0};
    for (int i = tid; i < NBLK; i += 256)
        #pragma unroll
        for (int q = 0; q < 5; ++q) vals[q] += (double)partials[(size_t)i * 8 + q];
    #pragma unroll
    for (int off = 1; off <= 32; off <<= 1)
        #pragma unroll
        for (int q = 0; q < 5; ++q) vals[q] += __shfl_xor(vals[q], off, 64);
    __shared__ double sred[4][5];
    const int wid = tid >> 6, lane = tid & 63;
    if (lane == 0)
        for (int q = 0; q < 5; ++q) sred[wid][q] = vals[q];
    __syncthreads();
    if (tid == 0) {
        double cm  = sred[0][0] + sred[1][0] + sred[2][0] + sred[3][0];
        double fs  = sred[0][1] + sred[1][1] + sred[2][1] + sred[3][1];
        double ms  = sred[0][2] + sred[1][2] + sred[2][2] + sred[3][2];
        double sx  = sred[0][3] + sred[1][3] + sred[2][3] + sred[3][3];
        double sxx = sred[0][4] + sred[1][4] + sred[2][4] + sred[3][4];
        double sz  = (double)TOTX;
        out[NT + TOTX + 0] = (float)(cm / (ms * (double)C_DIM));
        out[NT + TOTX + 1] = (float)(fs / (double)NT);
        out[NT + TOTX + 2] = (float)sqrt(fmax(0.0, (sxx - sx * sx / sz) / sz));
    }
}

// --------------------------------------------------------------------- x_d ----
__global__ __launch_bounds__(256) void xd_kernel(const float* __restrict__ mask,
                                                 const float* __restrict__ k,
                                                 float* __restrict__ out) {
    const int row = blockIdx.x * 256 + threadIdx.x;
    const int n = row >> 13, t = row & (T_DIM - 1);
    const int b = (int)out[row];
    const float m = mask[row];
    const float* kr = k + (size_t)b * C_DIM;
    float* xd = out + NT;
    #pragma unroll
    for (int c = 0; c < C_DIM; ++c)
        xd[((size_t)n * C_DIM + c) * T_DIM + t] = kr[c] * m;
}

// ----------------------------------------------------------------- launch ----
extern "C" void kernel_launch(void* const* d_in, const int* in_sizes, int n_in,
                              void* d_out, int out_size, void* d_ws, size_t ws_size,
                              hipStream_t stream) {
    (void)in_sizes; (void)n_in; (void)out_size; (void)d_ws; (void)ws_size;
    const float* x    = (const float*)d_in[0];
    const float* mask = (const float*)d_in[1];
    const float* k    = (const float*)d_in[2];
    float* out = (float*)d_out;

    kprep_kernel<<<KB / 256, 256, 0, stream>>>(k, out);
    argmin_kernel<<<NBLK, 256, 0, stream>>>(x, mask, out);
    fixup_kernel<<<2048, 256, 0, stream>>>(x, k, out);
    fixmerge_kernel<<<256, 256, 0, stream>>>(out);
    finalize_kernel<<<1, 256, 0, stream>>>(out);
    xd_kernel<<<NT / 256, 256, 0, stream>>>(mask, k, out);
}

// Round 19
// 78.782 us; speedup vs baseline: 40.3238x; 1.3076x over previous
//
#include <hip/hip_runtime.h>

#define T_DIM 8192
#define N_DIM 8
#define C_DIM 64
#define KB    2048
#define NT    (N_DIM * T_DIM)        // 65536 rows
#define TOTX  ((size_t)NT * C_DIM)   // 4194304 elements
#define NBLK  1024                   // argmin blocks (64 rows each)
#define LISTCAP 65536
#define TAU   0.04f

// Scratch inside out's x_d region (out + NT), overwritten LAST by xd_kernel.
// Offsets in FLOAT units from out+NT:
#define SCR_COUNT 0                   // int
#define SCR_LIST  16                  // int[65536]      -> ends 65552
#define SCR_PART  65792               // float[1024][8]  -> ends 73984
#define SCR_KK    76544               // float[2048]     -> ends 78592
#define SCR_K     81920               // f16x8 k9[16][9][128] (288 KB) -> 155648
#define SCR_FIX   262144              // float[65536][16] (4 MB) -> ends 1310720

typedef _Float16 half_t;
typedef _Float16 f16x8 __attribute__((ext_vector_type(8)));
typedef float    f32x16 __attribute__((ext_vector_type(16)));

// numpy pairwise sum (n=64) of squares (np-exact, fixup path).
__device__ __forceinline__ float np_sumsq64(const float* __restrict__ a) {
    float r[8];
    #pragma unroll
    for (int j = 0; j < 8; ++j) r[j] = __fmul_rn(a[j], a[j]);
    #pragma unroll
    for (int i = 8; i < 64; i += 8)
        #pragma unroll
        for (int j = 0; j < 8; ++j)
            r[j] = __fadd_rn(r[j], __fmul_rn(a[i + j], a[i + j]));
    return __fadd_rn(__fadd_rn(__fadd_rn(r[0], r[1]), __fadd_rn(r[2], r[3])),
                     __fadd_rn(__fadd_rn(r[4], r[5]), __fadd_rn(r[6], r[7])));
}

// ------------------------------------------------------------------ k prep ----
// 9-slot layout per 128-bin chunk: slots 0..7 = -2*f16(k) [slot][bin];
// slot 8 = (kn_hi, kn_lo, 0...) f16 pair of seq-fma ||k||^2 (injected via a
// 5th MFMA K-step). kk = np-exact ||k||^2 (fixup).
__global__ __launch_bounds__(256) void kprep_kernel(const float* __restrict__ k,
                                                    float* __restrict__ out) {
    float* base = out + NT;
    const int bin = blockIdx.x * 256 + threadIdx.x;   // grid 8 -> 2048
    if (bin == 0) ((int*)base)[SCR_COUNT] = 0;

    float kv[64];
    #pragma unroll
    for (int i = 0; i < 16; ++i)
        *(float4*)&kv[i * 4] = *(const float4*)(k + (size_t)bin * 64 + i * 4);

    float kn = 0.f;
    #pragma unroll
    for (int c = 0; c < 64; ++c) kn = fmaf(kv[c], kv[c], kn);
    base[SCR_KK + bin] = np_sumsq64(kv);

    f16x8* kscr = (f16x8*)(base + SCR_K);
    const int ch = bin >> 7, b127 = bin & 127;
    #pragma unroll
    for (int slot = 0; slot < 8; ++slot) {
        f16x8 h8;
        #pragma unroll
        for (int e = 0; e < 8; ++e)
            h8[e] = (half_t)(-2.f * (float)((half_t)kv[slot * 8 + e]));
        kscr[(size_t)ch * 1152 + slot * 128 + b127] = h8;
    }
    {
        half_t knh = (half_t)kn;
        half_t knl = (half_t)(kn - (float)knh);
        f16x8 k8;
        #pragma unroll
        for (int e = 0; e < 8; ++e) k8[e] = (half_t)0.f;
        k8[0] = knh; k8[1] = knl;
        kscr[(size_t)ch * 1152 + 1024 + b127] = k8;
    }
}

// ------------------------------------------------------------------ argmin ----
// Grid 1024, block = 64 rows x 4 waves: wave w -> (rg=w>>1 rows, hb=w&1 bins).
// BINS-AS-M: A=k (rows=bins), B=x (cols=x-rows). Each lane owns one x-row;
// 4 independent top-2 chains (12 tracking regs). 1-stage lane^32 merge.
__global__ __launch_bounds__(256, 2) void argmin_kernel(const float* __restrict__ x,
                                                        const float* __restrict__ mask,
                                                        float* __restrict__ out) {
    __shared__ __align__(16) f16x8 xhi_s[512];   // [8 slots][64 rows]
    __shared__ float psx[4][64], psxx[4][64];
    __shared__ float wres[2][64][3];

    float* base = out + NT;
    const int tid = threadIdx.x;
    const int l   = tid & 63, w = tid >> 6;
    const int col = l & 31, kg = l >> 5;
    const int rg  = w >> 1, hb = w & 1;
    const int r0  = blockIdx.x * 64;
    const int n   = r0 >> 13;
    const int t0  = r0 & (T_DIM - 1);

    // prologue: x load + f16-hi split + row stats (thread: row=tid&63, 2 slots)
    {
        const int row = tid & 63, sp = tid >> 6;
        float sx = 0.f, sxx = 0.f;
        #pragma unroll
        for (int ss = 0; ss < 2; ++ss) {
            const int slot = sp * 2 + ss;
            f16x8 h8;
            #pragma unroll
            for (int e = 0; e < 8; ++e) {
                float v = x[((size_t)n * C_DIM + slot * 8 + e) * T_DIM + t0 + row];
                h8[e] = (half_t)v;
                sx += v; sxx = fmaf(v, v, sxx);
            }
            xhi_s[slot * 64 + row] = h8;
        }
        psx[sp][row]  = sx;
        psxx[sp][row] = sxx;
    }
    __syncthreads();

    // x B-fragments: cols = rows rg*32 + col, K=64 over 4 k-steps + ones frag
    f16x8 a0 = xhi_s[(0 + kg) * 64 + rg * 32 + col];
    f16x8 a1 = xhi_s[(2 + kg) * 64 + rg * 32 + col];
    f16x8 a2 = xhi_s[(4 + kg) * 64 + rg * 32 + col];
    f16x8 a3 = xhi_s[(6 + kg) * 64 + rg * 32 + col];
    f16x8 aones;
    #pragma unroll
    for (int e = 0; e < 8; ++e) aones[e] = (half_t)0.f;
    if (kg == 0) { aones[0] = (half_t)1.f; aones[1] = (half_t)1.f; }

    // per-wave k base (bin half hb); chunk stride 1152 f16x8 (9 slots x 128)
    const f16x8* kf0 = (const f16x8*)(base + SCR_K) + (size_t)hb * 9216 + col;
    const int kgo = kg * 128;

    f32x16 zacc;
    #pragma unroll
    for (int r = 0; r < 16; ++r) zacc[r] = 0.f;

    // 4 independent top-2 chains: chain j handles acc entries 4j..4j+3
    float bv0 = __builtin_inff(), b20 = __builtin_inff(); int c0 = 0;
    float bv1 = __builtin_inff(), b21 = __builtin_inff(); int c1 = 0;
    float bv2 = __builtin_inff(), b22 = __builtin_inff(); int c2 = 0;
    float bv3 = __builtin_inff(), b23 = __builtin_inff(); int c3 = 0;

    f16x8 bA[4], bB[4], b4A, b4B;

#define LOADT(t, BH, B4)                                            \
    {                                                               \
        const f16x8* p = kf0 + (((t) >> 2) * 1152 + ((t) & 3) * 32);\
        BH[0] = p[kgo]; BH[1] = p[kgo + 256];                       \
        BH[2] = p[kgo + 512]; BH[3] = p[kgo + 768];                 \
        B4 = p[1024];                                               \
    }

#define UPD(J, RR, CODE)                                                     \
    {                                                                        \
        float sv = acc[RR];                                                  \
        float nb2;                                                           \
        asm("v_med3_f32 %0, %1, %2, %3"                                      \
            : "=v"(nb2) : "v"(sv), "v"(bv##J), "v"(b2##J));                  \
        b2##J = nb2;                                                         \
        if (sv < bv##J) { bv##J = sv; c##J = (CODE); }                       \
    }

#define COMPT(t, BH, B4)                                                     \
    {                                                                        \
        f32x16 acc = __builtin_amdgcn_mfma_f32_32x32x16_f16(B4, aones, zacc, 0, 0, 0); \
        acc = __builtin_amdgcn_mfma_f32_32x32x16_f16(BH[0], a0, acc, 0, 0, 0); \
        acc = __builtin_amdgcn_mfma_f32_32x32x16_f16(BH[1], a1, acc, 0, 0, 0); \
        acc = __builtin_amdgcn_mfma_f32_32x32x16_f16(BH[2], a2, acc, 0, 0, 0); \
        acc = __builtin_amdgcn_mfma_f32_32x32x16_f16(BH[3], a3, acc, 0, 0, 0); \
        const int cb = hb * 1024 + (t) * 32;                                 \
        UPD(0, 0, cb + 0)  UPD(0, 1, cb + 1)  UPD(0, 2, cb + 2)  UPD(0, 3, cb + 3) \
        UPD(1, 4, cb + 8)  UPD(1, 5, cb + 9)  UPD(1, 6, cb + 10) UPD(1, 7, cb + 11) \
        UPD(2, 8, cb + 16) UPD(2, 9, cb + 17) UPD(2, 10, cb + 18) UPD(2, 11, cb + 19) \
        UPD(3, 12, cb + 24) UPD(3, 13, cb + 25) UPD(3, 14, cb + 26) UPD(3, 15, cb + 27) \
    }

    LOADT(0, bA, b4A);
    #pragma unroll 1
    for (int t = 0; t < 30; t += 2) {
        LOADT(t + 1, bB, b4B);
        COMPT(t, bA, b4A);
        LOADT(t + 2, bA, b4A);
        COMPT(t + 1, bB, b4B);
    }
    LOADT(31, bB, b4B);
    COMPT(30, bA, b4A);
    COMPT(31, bB, b4B);
#undef LOADT
#undef COMPT
#undef UPD

    // add the lane-half bin offset (bins 4*hi of each crow group)
    const int hi4 = kg * 4;
    c0 += hi4; c1 += hi4; c2 += hi4; c3 += hi4;

    // merge 4 chains -> (bv, b2, bb)   [top-2 merge, tie -> lower code]
    float bv, b2; int bb;
    {
        float m01v; int m01c; float m01s;
        if (bv1 < bv0 || (bv1 == bv0 && c1 < c0)) { m01v = bv1; m01c = c1; }
        else                                      { m01v = bv0; m01c = c0; }
        m01s = fminf(fminf(b20, b21), fmaxf(bv0, bv1));
        float m23v; int m23c; float m23s;
        if (bv3 < bv2 || (bv3 == bv2 && c3 < c2)) { m23v = bv3; m23c = c3; }
        else                                      { m23v = bv2; m23c = c2; }
        m23s = fminf(fminf(b22, b23), fmaxf(bv2, bv3));
        if (m23v < m01v || (m23v == m01v && m23c < m01c)) { bv = m23v; bb = m23c; }
        else                                              { bv = m01v; bb = m01c; }
        b2 = fminf(fminf(m01s, m23s), fmaxf(m01v, m23v));
    }

    // single-stage lane^32 merge (two bin-subsets of the same x-row)
    {
        float ov = __shfl_xor(bv, 32, 64);
        float o2 = __shfl_xor(b2, 32, 64);
        int   ob = __shfl_xor(bb, 32, 64);
        b2 = fminf(fminf(b2, o2), fmaxf(bv, ov));
        if (ov < bv || (ov == bv && ob < bb)) { bv = ov; bb = ob; }
    }

    // lanes 0..31 hold final per-row results for this bin half
    if (kg == 0) {
        const int row_loc = rg * 32 + col;
        wres[hb][row_loc][0] = bv;
        wres[hb][row_loc][1] = b2;
        wres[hb][row_loc][2] = __int_as_float(bb);
    }
    __syncthreads();

    // final merge: threads 0..63 (wave 0) own one row each
    if (tid < 64) {
        const int row = tid;
        const float v0 = wres[0][row][0], v1 = wres[1][row][0];
        float fbv = v0; int fbb = __float_as_int(wres[0][row][2]);
        if (v1 < fbv) { fbv = v1; fbb = __float_as_int(wres[1][row][2]); }
        const float fb2 = fminf(fminf(wres[0][row][1], wres[1][row][1]),
                                fmaxf(v0, v1));
        out[r0 + row] = (float)fbb;
        if (fb2 - fbv < TAU) {
            int idx = atomicAdd((int*)base + SCR_COUNT, 1);
            if (idx < LISTCAP) ((int*)base + SCR_LIST)[idx] = r0 + row;
        }
        float sx = 0.f, sxx = 0.f;
        #pragma unroll
        for (int sp = 0; sp < 4; ++sp) { sx += psx[sp][row]; sxx += psxx[sp][row]; }
        const float m  = mask[r0 + row];
        const float d2 = sxx + fbv;
        float vals[5] = { m * d2, d2, m, sx, sxx };
        #pragma unroll
        for (int off = 1; off <= 32; off <<= 1)
            #pragma unroll
            for (int q = 0; q < 5; ++q) vals[q] += __shfl_xor(vals[q], off, 64);
        if (tid == 0) {
            float* partials = base + SCR_PART;
            #pragma unroll
            for (int q = 0; q < 5; ++q)
                partials[(size_t)blockIdx.x * 8 + q] = vals[q];
        }
    }
}

// ------------------------------------------------------------------ fixup ----
// Work unit = (32-row batch) x (256-bin chunk). Each thread scans 32
// contiguous bins as 2 independent np-f32-exact chains; per-(row,chunk)
// partial (value,bin) -> SCR_FIX.
__global__ __launch_bounds__(256) void fixup_kernel(const float* __restrict__ x,
                                                    const float* __restrict__ k,
                                                    float* __restrict__ out) {
    __shared__ float xs[32][65];
    __shared__ float sxx_s[32];
    __shared__ float redv[256];
    __shared__ int   redb[256];

    const int tid = threadIdx.x;
    float* base = out + NT;
    const int* count    = (const int*)base + SCR_COUNT;
    const int* flaglist = (const int*)base + SCR_LIST;
    const float* kk     = base + SCR_KK;
    float* fix          = base + SCR_FIX;
    int cnt = *count;
    if (cnt > LISTCAP) cnt = LISTCAP;
    const int nb8 = ((cnt + 31) >> 5) << 3;

    const int rloc = tid & 31, part = tid >> 5;

    for (int wk = blockIdx.x; wk < nb8; wk += gridDim.x) {
        const int bi = wk >> 3, chunk = wk & 7;
        int li = bi * 32 + rloc;
        if (li >= cnt) li = bi * 32;                 // clamp (duplicate row ok)
        const int row = flaglist[li];
        const int n = row >> 13, t = row & (T_DIM - 1);
        #pragma unroll
        for (int e = 0; e < 8; ++e)
            xs[rloc][part * 8 + e] = x[((size_t)n * C_DIM + part * 8 + e) * T_DIM + t];
        __syncthreads();
        if (tid < 32) sxx_s[tid] = np_sumsq64(&xs[tid][0]);
        __syncthreads();

        float xr[64];
        #pragma unroll
        for (int c = 0; c < 64; ++c) xr[c] = xs[rloc][c];
        const float xx = sxx_s[rloc];

        float bv = __builtin_inff();
        int   bb = 0x7fffffff;
        const int bbase = chunk * 256 + part * 32;
        #pragma unroll 1
        for (int i = 0; i < 32; i += 2) {
            const int b0 = bbase + i;
            const int b1 = b0 + 1;
            const float* k0 = k + (size_t)b0 * 64;
            const float* k1 = k + (size_t)b1 * 64;
            float d0 = 0.f, d1 = 0.f;
            #pragma unroll
            for (int c = 0; c < 64; ++c) {
                d0 = fmaf(xr[c], k0[c], d0);
                d1 = fmaf(xr[c], k1[c], d1);
            }
            float s0 = __fadd_rn(__fsub_rn(xx, __fadd_rn(d0, d0)), kk[b0]);
            float s1 = __fadd_rn(__fsub_rn(xx, __fadd_rn(d1, d1)), kk[b1]);
            if (s0 < bv || (s0 == bv && b0 < bb)) { bv = s0; bb = b0; }
            if (s1 < bv || (s1 == bv && b1 < bb)) { bv = s1; bb = b1; }
        }
        redv[tid] = bv; redb[tid] = bb;
        __syncthreads();
        if (tid < 32) {
            float fv = redv[tid]; int fb = redb[tid];
            #pragma unroll
            for (int p = 1; p < 8; ++p) {
                float ov = redv[p * 32 + tid];
                int   ob = redb[p * 32 + tid];
                if (ov < fv || (ov == fv && ob < fb)) { fv = ov; fb = ob; }
            }
            const int fi = bi * 32 + tid;
            if (fi < cnt) {
                fix[(size_t)fi * 16 + chunk * 2]     = fv;
                fix[(size_t)fi * 16 + chunk * 2 + 1] = __int_as_float(fb);
            }
        }
        __syncthreads();
    }
}

// ---------------------------------------------------------------- fixmerge ----
__global__ __launch_bounds__(256) void fixmerge_kernel(float* __restrict__ out) {
    float* base = out + NT;
    const int* count    = (const int*)base + SCR_COUNT;
    const int* flaglist = (const int*)base + SCR_LIST;
    const float* fix    = base + SCR_FIX;
    int cnt = *count;
    if (cnt > LISTCAP) cnt = LISTCAP;

    for (int fi = blockIdx.x * 256 + threadIdx.x; fi < cnt;
         fi += gridDim.x * 256) {
        const float* p = fix + (size_t)fi * 16;
        float bv = p[0];
        int   bb = __float_as_int(p[1]);
        #pragma unroll
        for (int c = 1; c < 8; ++c) {
            float v = p[c * 2];
            int   b = __float_as_int(p[c * 2 + 1]);
            if (v < bv || (v == bv && b < bb)) { bv = v; bb = b; }
        }
        out[flaglist[fi]] = (float)bb;
    }
}

// ------------------------------------------------------------- finalize ----
__global__ __launch_bounds__(256) void finalize_kernel(float* __restrict__ out) {
    const float* partials = (out + NT) + SCR_PART;
    const int tid = threadIdx.x;
    double vals[5] = {0, 0, 0, 0, 0};
    for (int i = tid; i < NBLK; i += 256)
        #pragma unroll
        for (int q = 0; q < 5; ++q) vals[q] += (double)partials[(size_t)i * 8 + q];
    #pragma unroll
    for (int off = 1; off <= 32; off <<= 1)
        #pragma unroll
        for (int q = 0; q < 5; ++q) vals[q] += __shfl_xor(vals[q], off, 64);
    __shared__ double sred[4][5];
    const int wid = tid >> 6, lane = tid & 63;
    if (lane == 0)
        for (int q = 0; q < 5; ++q) sred[wid][q] = vals[q];
    __syncthreads();
    if (tid == 0) {
        double cm  = sred[0][0] + sred[1][0] + sred[2][0] + sred[3][0];
        double fs  = sred[0][1] + sred[1][1] + sred[2][1] + sred[3][1];
        double ms  = sred[0][2] + sred[1][2] + sred[2][2] + sred[3][2];
        double sx  = sred[0][3] + sred[1][3] + sred[2][3] + sred[3][3];
        double sxx = sred[0][4] + sred[1][4] + sred[2][4] + sred[3][4];
        double sz  = (double)TOTX;
        out[NT + TOTX + 0] = (float)(cm / (ms * (double)C_DIM));
        out[NT + TOTX + 1] = (float)(fs / (double)NT);
        out[NT + TOTX + 2] = (float)sqrt(fmax(0.0, (sxx - sx * sx / sz) / sz));
    }
}

// --------------------------------------------------------------------- x_d ----
__global__ __launch_bounds__(256) void xd_kernel(const float* __restrict__ mask,
                                                 const float* __restrict__ k,
                                                 float* __restrict__ out) {
    const int row = blockIdx.x * 256 + threadIdx.x;
    const int n = row >> 13, t = row & (T_DIM - 1);
    const int b = (int)out[row];
    const float m = mask[row];
    const float* kr = k + (size_t)b * C_DIM;
    float* xd = out + NT;
    #pragma unroll
    for (int c = 0; c < C_DIM; ++c)
        xd[((size_t)n * C_DIM + c) * T_DIM + t] = kr[c] * m;
}

// ----------------------------------------------------------------- launch ----
extern "C" void kernel_launch(void* const* d_in, const int* in_sizes, int n_in,
                              void* d_out, int out_size, void* d_ws, size_t ws_size,
                              hipStream_t stream) {
    (void)in_sizes; (void)n_in; (void)out_size; (void)d_ws; (void)ws_size;
    const float* x    = (const float*)d_in[0];
    const float* mask = (const float*)d_in[1];
    const float* k    = (const float*)d_in[2];
    float* out = (float*)d_out;

    kprep_kernel<<<KB / 256, 256, 0, stream>>>(k, out);
    argmin_kernel<<<NBLK, 256, 0, stream>>>(x, mask, out);
    fixup_kernel<<<2048, 256, 0, stream>>>(x, k, out);
    fixmerge_kernel<<<256, 256, 0, stream>>>(out);
    finalize_kernel<<<1, 256, 0, stream>>>(out);
    xd_kernel<<<NT / 256, 256, 0, stream>>>(mask, k, out);
}